// Round 17
// baseline (413.359 us; speedup 1.0000x reference)
//
#include <hip/hip_runtime.h>
#include <cstdint>
#include <cstddef>

#define NEG_SLOPE 0.2f
#define BSHIFT 8          // coarse bucket = dst >> 8 (256 dst nodes / bucket)

typedef __attribute__((ext_vector_type(8))) short short8;   // 8 bf16 = 4 VGPR (MFMA A/B frag)
typedef __attribute__((ext_vector_type(4))) float f32x4;    // MFMA C/D frag

__device__ __forceinline__ float leakyf(float x) { return x > 0.f ? x : NEG_SLOPE * x; }
__device__ __forceinline__ float fast_tanh(float x) {
    float e = __expf(2.f * x);
    return 1.f - 2.f / (e + 1.f);
}
__device__ __forceinline__ unsigned short f2bf(float x) {   // f32 -> bf16 RNE
    unsigned u = __float_as_uint(x);
    unsigned r = u + 0x7FFFu + ((u >> 16) & 1u);
    return (unsigned short)(r >> 16);
}

// ---------------- build extended B matrix for proj MFMA ----------------
// BExt[col][k] (col-major, bf16), 160 cols: [0,128) = W; [128,136) = W@P(att0);
// [136,144) = W@P(att1); [144,152) = W@P(att2); [152,160) = 0.  (att null -> 0)
// beArr[24] = bias @ P for the three att vecs.  e = x@(W@P) + b@P  (linearity of e-dots).
__global__ void bext_kernel(const float* __restrict__ W, const float* __restrict__ bias,
                            const float* __restrict__ att0, const float* __restrict__ att1,
                            const float* __restrict__ att2,
                            unsigned short* __restrict__ BExt, float* __restrict__ beArr)
{
    const int t = threadIdx.x;  // 256
    // plain W columns
    for (int task = t; task < 128 * 128; task += 256) {
        int col = task >> 7, k = task & 127;
        BExt[(size_t)col * 128 + k] = f2bf(W[(size_t)k * 128 + col]);
    }
    // e-columns (32 cols: 3 att vecs x 8 heads + 8 pad)
    for (int task = t; task < 32 * 128; task += 256) {
        int col = task >> 7, k = task & 127;
        int vec = col >> 3, h = col & 7;
        const float* att = (vec == 0) ? att0 : (vec == 1) ? att1 : (vec == 2) ? att2 : nullptr;
        float s = 0.f;
        if (att) {
            #pragma unroll
            for (int d = 0; d < 16; ++d) s = fmaf(W[(size_t)k * 128 + h * 16 + d], att[h * 16 + d], s);
        }
        BExt[(size_t)(128 + col) * 128 + k] = f2bf(s);
    }
    if (t < 24) {
        int vec = t >> 3, h = t & 7;
        const float* att = (vec == 0) ? att0 : (vec == 1) ? att1 : att2;
        float s = 0.f;
        if (att) {
            #pragma unroll
            for (int d = 0; d < 16; ++d) s = fmaf(bias[h * 16 + d], att[h * 16 + d], s);
        }
        beArr[t] = s;
    }
}

// ---------------- projection via bf16 MFMA (h cols + fused e-dot cols) ----------------
// 128-row block, 4 waves; wave w owns rows [32w,32w+32) as TWO 16-row A-frags; 10 col-tiles
// (8 h + 2 e).  A from XOR-swizzled LDS bf16 tile; B from L2-resident BExt.
// C layout (verified): col = lane&15, row = (lane>>4)*4 + reg.
__global__ __launch_bounds__(256) void proj_mfma(
    const float* __restrict__ x, const unsigned short* __restrict__ BExt,
    const float* __restrict__ bias, const float* __restrict__ beArr,
    unsigned short* __restrict__ hout,
    float* __restrict__ e0, float* __restrict__ e1, float* __restrict__ e2, int N)
{
    __shared__ short atile[128 * 128];  // 32 KB bf16, 16B-chunk XOR-swizzled
    const int t = threadIdx.x;
    const int row0 = blockIdx.x * 128;
    // ---- stage A-tile: thread t -> row t>>1, k-chunks (t&1)*8 .. +7 ----
    {
        const int row = t >> 1, q8 = t & 1;
        const int gr = row0 + row;
        #pragma unroll
        for (int c = 0; c < 8; ++c) {
            const int kc = q8 * 8 + c;
            float4 l0 = make_float4(0.f, 0.f, 0.f, 0.f), l1 = l0;
            if (gr < N) {
                l0 = *(const float4*)(x + (size_t)gr * 128 + kc * 8);
                l1 = *(const float4*)(x + (size_t)gr * 128 + kc * 8 + 4);
            }
            int4 u;
            u.x = (int)f2bf(l0.x) | ((int)f2bf(l0.y) << 16);
            u.y = (int)f2bf(l0.z) | ((int)f2bf(l0.w) << 16);
            u.z = (int)f2bf(l1.x) | ((int)f2bf(l1.y) << 16);
            u.w = (int)f2bf(l1.z) | ((int)f2bf(l1.w) << 16);
            const int chunk = row * 16 + kc;
            const int chunk_sw = chunk ^ (row & 7);
            *(int4*)((char*)atile + chunk_sw * 16) = u;
        }
    }
    __syncthreads();
    const int w = t >> 6, l = t & 63;
    const int lrow = l & 15, lk = l >> 4;
    f32x4 acc[2][10];
    #pragma unroll
    for (int a = 0; a < 2; ++a)
        #pragma unroll
        for (int ct = 0; ct < 10; ++ct) { acc[a][ct][0] = 0.f; acc[a][ct][1] = 0.f; acc[a][ct][2] = 0.f; acc[a][ct][3] = 0.f; }
    #pragma unroll
    for (int ks = 0; ks < 4; ++ks) {
        short8 afr[2];
        #pragma unroll
        for (int a = 0; a < 2; ++a) {
            const int rowl = w * 32 + a * 16 + lrow;
            const int chunk = rowl * 16 + ks * 4 + lk;
            const int chunk_sw = chunk ^ (rowl & 7);
            afr[a] = *(short8*)((char*)atile + chunk_sw * 16);
        }
        #pragma unroll
        for (int ct = 0; ct < 10; ++ct) {
            const unsigned short* bp = BExt + ((size_t)(ct * 16 + lrow) * 128 + ks * 32 + lk * 8);
            short8 bfr = *(const short8*)bp;
            acc[0][ct] = __builtin_amdgcn_mfma_f32_16x16x32_bf16(afr[0], bfr, acc[0][ct], 0, 0, 0);
            acc[1][ct] = __builtin_amdgcn_mfma_f32_16x16x32_bf16(afr[1], bfr, acc[1][ct], 0, 0, 0);
        }
    }
    // ---- epilogue: h = acc + bias (bf16 store); e = acc + be (f32 store) ----
    #pragma unroll
    for (int ct = 0; ct < 8; ++ct) {
        const int col = ct * 16 + lrow;
        const float bv = bias[col];
        #pragma unroll
        for (int a = 0; a < 2; ++a) {
            #pragma unroll
            for (int r = 0; r < 4; ++r) {
                const int grow = row0 + w * 32 + a * 16 + lk * 4 + r;
                if (grow < N) hout[(size_t)grow * 128 + col] = f2bf(acc[a][ct][r] + bv);
            }
        }
    }
    {   // ct = 8: e0 (lrow<8) / e1 (lrow>=8)
        const float be = beArr[lrow];
        float* tgt = (lrow < 8) ? e0 : e1;
        const int head = lrow & 7;
        if (tgt) {
            #pragma unroll
            for (int a = 0; a < 2; ++a) {
                #pragma unroll
                for (int r = 0; r < 4; ++r) {
                    const int grow = row0 + w * 32 + a * 16 + lk * 4 + r;
                    if (grow < N) tgt[(size_t)grow * 8 + head] = acc[a][8][r] + be;
                }
            }
        }
    }
    if (lrow < 8 && e2) {   // ct = 9: e2
        const float be = beArr[16 + lrow];
        #pragma unroll
        for (int a = 0; a < 2; ++a) {
            #pragma unroll
            for (int r = 0; r < 4; ++r) {
                const int grow = row0 + w * 32 + a * 16 + lk * 4 + r;
                if (grow < N) e2[(size_t)grow * 8 + lrow] = acc[a][9][r] + be;
            }
        }
    }
}

// ================= two-level bucket CSR build =================
__global__ __launch_bounds__(256) void bucket_hist(
    const int* __restrict__ dstg, int Eg, const int* __restrict__ dstd, int Ed,
    int NBg, int NBtot, int* __restrict__ bucketCnt)
{
    __shared__ int h[1024];
    const int t = threadIdx.x;
    for (int j = t; j < NBtot; j += 256) h[j] = 0;
    __syncthreads();
    const int Etot = Eg + Ed;
    const int base = blockIdx.x * 4096;
    #pragma unroll
    for (int k = 0; k < 16; ++k) {
        int i = base + k * 256 + t;
        if (i < Etot) {
            int b = (i < Eg) ? (dstg[i] >> BSHIFT) : NBg + (dstd[i - Eg] >> BSHIFT);
            atomicAdd(&h[b], 1);
        }
    }
    __syncthreads();
    for (int j = t; j < NBtot; j += 256) {
        int c = h[j];
        if (c) atomicAdd(&bucketCnt[j], c);
    }
}

__global__ void bucket_scan(const int* __restrict__ bucketCnt, int NBtot, int Etot,
                            int* __restrict__ bucketBase, int* __restrict__ bucketCursor)
{
    __shared__ int s[1024];
    int t = threadIdx.x;
    int v = (t < NBtot) ? bucketCnt[t] : 0;
    s[t] = v;
    __syncthreads();
    for (int o = 1; o < 1024; o <<= 1) {
        int add = (t >= o) ? s[t - o] : 0;
        __syncthreads();
        s[t] += add;
        __syncthreads();
    }
    if (t < NBtot) {
        int e = s[t] - v;
        bucketBase[t] = e;
        bucketCursor[t] = e;
    }
    if (t == 0) bucketBase[NBtot] = Etot;
}

__global__ __launch_bounds__(256) void bucket_scatter(
    const int* __restrict__ dstg, const int* __restrict__ srcg, int Eg,
    const int* __restrict__ dstd, const int* __restrict__ srcd, int Ed,
    int NBg, int NBtot, int* __restrict__ bucketCursor, unsigned* __restrict__ coarse)
{
    __shared__ int h[800];
    __shared__ int basearr[800];
    __shared__ int cur[800];
    const int t = threadIdx.x;
    for (int j = t; j < NBtot; j += 256) h[j] = 0;
    __syncthreads();
    const int Etot = Eg + Ed;
    const int base = blockIdx.x * 4096;
    int bk[16];
    unsigned pk[16];
    #pragma unroll
    for (int k = 0; k < 16; ++k) {
        int i = base + k * 256 + t;
        bk[k] = -1;
        if (i < Etot) {
            int dst, src, goff;
            if (i < Eg) { dst = dstg[i]; src = srcg[i]; goff = 0; }
            else        { dst = dstd[i - Eg]; src = srcd[i - Eg]; goff = NBg; }
            bk[k] = goff + (dst >> BSHIFT);
            pk[k] = (unsigned)src | ((unsigned)(dst & 255) << 24);
            atomicAdd(&h[bk[k]], 1);
        }
    }
    __syncthreads();
    for (int j = t; j < NBtot; j += 256) {
        int c = h[j];
        basearr[j] = c ? atomicAdd(&bucketCursor[j], c) : 0;
        cur[j] = 0;
    }
    __syncthreads();
    #pragma unroll
    for (int k = 0; k < 16; ++k) {
        if (bk[k] >= 0) {
            int r = atomicAdd(&cur[bk[k]], 1);
            coarse[basearr[bk[k]] + r] = pk[k];
        }
    }
}

__global__ __launch_bounds__(256) void bucket_sort(
    const unsigned* __restrict__ coarse, const int* __restrict__ bucketBase,
    int NBg, int Eg, int Ed, int N,
    int* __restrict__ offg, int* __restrict__ offd,
    int* __restrict__ srcs_g, int* __restrict__ srcs_d)
{
    __shared__ int hist[256];
    __shared__ int excl[256];
    __shared__ int cur[256];
    const int b = blockIdx.x;
    const int t = threadIdx.x;
    const int s0 = bucketBase[b], s1 = bucketBase[b + 1];
    const int cnt = s1 - s0;
    const bool isg = b < NBg;
    const int d0 = (isg ? b : b - NBg) << BSHIFT;
    hist[t] = 0;
    __syncthreads();
    for (int i = t; i < cnt; i += 256) {
        unsigned p = coarse[s0 + i];
        atomicAdd(&hist[p >> 24], 1);
    }
    __syncthreads();
    int v = hist[t];
    excl[t] = v;
    __syncthreads();
    for (int o = 1; o < 256; o <<= 1) {
        int add = (t >= o) ? excl[t - o] : 0;
        __syncthreads();
        excl[t] += add;
        __syncthreads();
    }
    const int e = excl[t] - v;  // exclusive prefix within bucket
    const int localBase = isg ? s0 : s0 - Eg;
    const int d = d0 + t;
    if (d < N) {
        if (isg) offg[d] = localBase + e;
        else     offd[d] = localBase + e;
    }
    cur[t] = e;
    __syncthreads();
    int* outp = isg ? srcs_g : srcs_d;
    for (int i = t; i < cnt; i += 256) {
        unsigned p = coarse[s0 + i];
        int r = atomicAdd(&cur[p >> 24], 1);
        outp[localBase + r] = (int)(p & 0xFFFFFFu);
    }
    if (b == 0 && t == 0) { offg[N] = Eg; offd[N] = Ed; }
}

// ---------------- per-dst-node softmax aggregation (1 wave per node) ----------------
// xs BF16; f32 accumulate; no-max softmax (logits bounded ~3, shift-invariant).
__global__ __launch_bounds__(256) void aggregate_kernel(
    const unsigned short* __restrict__ xs,  // [Ns,128] projected src feats (bf16)
    const float* __restrict__ esrc,      // [Ns,8]
    const float* __restrict__ edst,      // [Nd,8]
    const int* __restrict__ off,         // [Nd+1]
    const int* __restrict__ srcsorted,   // [E] src ids bucketed by dst
    float* __restrict__ outp,            // [Nd,128]
    int Nd)
{
    __shared__ float exbuf[4][64 * 8];
    const int lane = threadIdx.x & 63;
    const int wslot = threadIdx.x >> 6;
    const int n = blockIdx.x * 4 + wslot;
    if (n >= Nd) return;
    const int o0 = off[n], o1 = off[n + 1];
    const int deg = o1 - o0;
    const int li = lane & 31, half = lane >> 5;
    const int j0 = li * 4;       // this lane's 4 cols (within its half)
    const int hh = li >> 2;      // head owning those cols
    if (deg == 0) {
        if (half == 0) *(float4*)(outp + (size_t)n * 128 + j0) = make_float4(0.f, 0.f, 0.f, 0.f);
        return;
    }
    float ed[8];
    {
        float4 a = *(const float4*)(edst + (size_t)n * 8);
        float4 b = *(const float4*)(edst + (size_t)n * 8 + 4);
        ed[0] = a.x; ed[1] = a.y; ed[2] = a.z; ed[3] = a.w;
        ed[4] = b.x; ed[5] = b.y; ed[6] = b.z; ed[7] = b.w;
    }
    if (deg <= 64) {
        const bool act = lane < deg;
        int s = act ? srcsorted[o0 + lane] : 0;   // coalesced
        float exv[8];
        {
            float4 ea = make_float4(0.f, 0.f, 0.f, 0.f), eb = ea;
            if (act) {
                ea = *(const float4*)(esrc + (size_t)s * 8);
                eb = *(const float4*)(esrc + (size_t)s * 8 + 4);
            }
            float a[8] = {ea.x, ea.y, ea.z, ea.w, eb.x, eb.y, eb.z, eb.w};
            #pragma unroll
            for (int h2 = 0; h2 < 8; ++h2)
                exv[h2] = act ? __expf(leakyf(a[h2] + ed[h2])) : 0.f;
        }
        *(float4*)(&exbuf[wslot][lane * 8])     = make_float4(exv[0], exv[1], exv[2], exv[3]);
        *(float4*)(&exbuf[wslot][lane * 8 + 4]) = make_float4(exv[4], exv[5], exv[6], exv[7]);
        float4 num = make_float4(0.f, 0.f, 0.f, 0.f);
        float den = 0.f;
        const int iters = (deg + 1) >> 1;
        #pragma unroll 2
        for (int k = 0; k < iters; ++k) {
            int i = 2 * k + half;
            if (i < deg) {
                int si = __shfl(s, i);
                float wgt = exbuf[wslot][i * 8 + hh];
                int2 xv2 = *(const int2*)(xs + (size_t)si * 128 + j0);
                unsigned ux = (unsigned)xv2.x, uy = (unsigned)xv2.y;
                float x0 = __uint_as_float(ux << 16);
                float x1 = __uint_as_float(ux & 0xFFFF0000u);
                float x2 = __uint_as_float(uy << 16);
                float x3 = __uint_as_float(uy & 0xFFFF0000u);
                num.x = fmaf(wgt, x0, num.x);
                num.y = fmaf(wgt, x1, num.y);
                num.z = fmaf(wgt, x2, num.z);
                num.w = fmaf(wgt, x3, num.w);
                den += wgt;
            }
        }
        num.x += __shfl_xor(num.x, 32);
        num.y += __shfl_xor(num.y, 32);
        num.z += __shfl_xor(num.z, 32);
        num.w += __shfl_xor(num.w, 32);
        den += __shfl_xor(den, 32);
        if (half == 0) {
            float inv = 1.f / (den + 1e-16f);
            float4 r;
            r.x = fmaxf(num.x * inv, 0.f);
            r.y = fmaxf(num.y * inv, 0.f);
            r.z = fmaxf(num.z * inv, 0.f);
            r.w = fmaxf(num.w * inv, 0.f);
            *(float4*)(outp + (size_t)n * 128 + j0) = r;
        }
        return;
    }
    // ---- slow path (deg > 64), no-max version ----
    {
        const int j0b = lane * 2;
        const int h = lane >> 3;
        float edh;
        {
            float u4a = (h & 4) ? ed[4] : ed[0];
            float u4b = (h & 4) ? ed[5] : ed[1];
            float u4c = (h & 4) ? ed[6] : ed[2];
            float u4d = (h & 4) ? ed[7] : ed[3];
            float u2a = (h & 2) ? u4c : u4a;
            float u2b = (h & 2) ? u4d : u4b;
            edh = (h & 1) ? u2b : u2a;
        }
        float den = 0.f, num0 = 0.f, num1 = 0.f;
        for (int base = 0; base < deg; base += 64) {
            int ii = base + lane;
            bool act = ii < deg;
            int sreg = srcsorted[o0 + (act ? ii : 0)];
            int cl = deg - base;
            if (cl > 64) cl = 64;
            for (int i = 0; i < cl; ++i) {
                int s = __shfl(sreg, i);
                float ev = esrc[(size_t)s * 8 + h];
                float ex = __expf(leakyf(ev + edh));
                unsigned uv = *(const unsigned*)(xs + (size_t)s * 128 + j0b);
                float x0 = __uint_as_float(uv << 16);
                float x1 = __uint_as_float(uv & 0xFFFF0000u);
                num0 = fmaf(ex, x0, num0);
                num1 = fmaf(ex, x1, num1);
                den += ex;
            }
        }
        float inv = 1.f / (den + 1e-16f);
        float r0 = num0 * inv, r1 = num1 * inv;
        r0 = r0 > 0.f ? r0 : 0.f;
        r1 = r1 > 0.f ? r1 : 0.f;
        *(float2*)(outp + (size_t)n * 128 + j0b) = make_float2(r0, r1);
    }
}

// ---------------- Wk transpose + bf16 convert (one-time per launch) ----------------
__global__ void wkt_kernel(const float* __restrict__ Wk, unsigned short* __restrict__ WkT) {
    int c = threadIdx.x;  // 128 threads = one column each
    for (int k = 0; k < 128; ++k)
        WkT[c * 128 + k] = f2bf(Wk[(size_t)k * 128 + c]);
}

// ---------------- semantic attention scores via bf16 MFMA ----------------
__global__ __launch_bounds__(256) void score2_mfma(
    const float* __restrict__ gg, const float* __restrict__ dg,
    const unsigned short* __restrict__ WkT,
    const float* __restrict__ bk, const float* __restrict__ q,
    float* __restrict__ scoreAcc, int N)
{
    __shared__ short atile[128 * 128];  // 32 KB bf16, 16B-chunk XOR-swizzled
    __shared__ float sred[4];
    const int t = threadIdx.x;
    const int row0 = blockIdx.x * 64;
    {
        const int row = t >> 1, q8 = t & 1;
        const int gr = row0 + (row & 63);
        const float* srcp = (row < 64) ? gg : dg;
        #pragma unroll
        for (int c = 0; c < 8; ++c) {
            const int kc = q8 * 8 + c;
            float4 l0 = make_float4(0.f, 0.f, 0.f, 0.f), l1 = l0;
            if (gr < N) {
                l0 = *(const float4*)(srcp + (size_t)gr * 128 + kc * 8);
                l1 = *(const float4*)(srcp + (size_t)gr * 128 + kc * 8 + 4);
            }
            int4 u;
            u.x = (int)f2bf(l0.x) | ((int)f2bf(l0.y) << 16);
            u.y = (int)f2bf(l0.z) | ((int)f2bf(l0.w) << 16);
            u.z = (int)f2bf(l1.x) | ((int)f2bf(l1.y) << 16);
            u.w = (int)f2bf(l1.z) | ((int)f2bf(l1.w) << 16);
            const int chunk = row * 16 + kc;
            const int chunk_sw = chunk ^ (row & 7);
            *(int4*)((char*)atile + chunk_sw * 16) = u;
        }
    }
    __syncthreads();
    const int w = t >> 6, l = t & 63;
    const int lrow = l & 15, lk = l >> 4;
    f32x4 acc[2][8];
    #pragma unroll
    for (int a = 0; a < 2; ++a)
        #pragma unroll
        for (int ct = 0; ct < 8; ++ct) { acc[a][ct][0] = 0.f; acc[a][ct][1] = 0.f; acc[a][ct][2] = 0.f; acc[a][ct][3] = 0.f; }
    #pragma unroll
    for (int ks = 0; ks < 4; ++ks) {
        short8 afr[2];
        #pragma unroll
        for (int a = 0; a < 2; ++a) {
            const int rowl = w * 32 + a * 16 + lrow;
            const int chunk = rowl * 16 + ks * 4 + lk;
            const int chunk_sw = chunk ^ (rowl & 7);
            afr[a] = *(short8*)((char*)atile + chunk_sw * 16);
        }
        #pragma unroll
        for (int ct = 0; ct < 8; ++ct) {
            const unsigned short* bp = WkT + ((size_t)(ct * 16 + lrow) * 128 + ks * 32 + lk * 8);
            short8 bfr = *(const short8*)bp;
            acc[0][ct] = __builtin_amdgcn_mfma_f32_16x16x32_bf16(afr[0], bfr, acc[0][ct], 0, 0, 0);
            acc[1][ct] = __builtin_amdgcn_mfma_f32_16x16x32_bf16(afr[1], bfr, acc[1][ct], 0, 0, 0);
        }
    }
    float s = 0.f;
    #pragma unroll
    for (int ct = 0; ct < 8; ++ct) {
        const int col = ct * 16 + lrow;
        const float bkv = bk[col];
        const float qv = q[col];
        #pragma unroll
        for (int a = 0; a < 2; ++a) {
            #pragma unroll
            for (int r = 0; r < 4; ++r) {
                const int rloc = a * 16 + lk * 4 + r;
                const int grow = row0 + ((w * 32 + rloc) & 63);
                if (grow < N) s = fmaf(fast_tanh(acc[a][ct][r] + bkv), qv, s);
            }
        }
    }
    #pragma unroll
    for (int o = 1; o < 64; o <<= 1) s += __shfl_xor(s, o);
    if (l == 0) sred[w] = s;
    __syncthreads();
    if (t == 0) {
        float pg = sred[0] + sred[1];   // waves 0,1 = gg rows
        float pd = sred[2] + sred[3];   // waves 2,3 = dg rows
        int slot = blockIdx.x & 63;
        atomicAdd(&scoreAcc[slot], pg);
        atomicAdd(&scoreAcc[64 + slot], pd);
    }
}

// ---------------- tiny: reduce 2x64 score slots -> softmax betas ----------------
__global__ void beta_kernel(float* __restrict__ scoreAcc, float invN) {
    int t = threadIdx.x;  // 64 threads
    float v0 = scoreAcc[t];
    float v1 = scoreAcc[64 + t];
    #pragma unroll
    for (int o = 1; o < 64; o <<= 1) {
        v0 += __shfl_xor(v0, o);
        v1 += __shfl_xor(v1, o);
    }
    if (t == 0) {
        float s0 = v0 * invN, s1 = v1 * invN;
        float mx = fmaxf(s0, s1);
        float e0 = __expf(s0 - mx), e1 = __expf(s1 - mx);
        float inv = 1.f / (e0 + e1);
        scoreAcc[128] = e0 * inv;
        scoreAcc[129] = e1 * inv;
    }
}

// ---------------- final: beta blend + @W_lin + b_lin (W_lin staged in LDS) ----------------
__global__ __launch_bounds__(256) void final_kernel(
    const float* __restrict__ gg, const float* __restrict__ dg,
    const float* __restrict__ beta,   // scoreAcc+128: {beta0, beta1}
    const float* __restrict__ Wl, const float* __restrict__ bl,
    float* __restrict__ outp, int N)
{
    __shared__ float wlds[128 * 64];  // 32 KB — whole W_lin
    __shared__ float glds[32 * 128];  // 16 KB — blended tile
    const int t = threadIdx.x;
    #pragma unroll
    for (int p = 0; p < 8; ++p) {
        int idx = (t + 256 * p) * 4;
        *(float4*)(wlds + idx) = *(const float4*)(Wl + idx);
    }
    const float bet0 = beta[0], bet1 = beta[1];
    const int row0 = blockIdx.x * 32;
    #pragma unroll
    for (int p = 0; p < 4; ++p) {
        int idx = t + 256 * p;
        int r = idx >> 5;
        int c4 = idx & 31;
        float4 a = make_float4(0.f, 0.f, 0.f, 0.f), b = a, g;
        if (row0 + r < N) {
            a = *(const float4*)(gg + (size_t)(row0 + r) * 128 + c4 * 4);
            b = *(const float4*)(dg + (size_t)(row0 + r) * 128 + c4 * 4);
        }
        g.x = bet0 * a.x + bet1 * b.x;
        g.y = bet0 * a.y + bet1 * b.y;
        g.z = bet0 * a.z + bet1 * b.z;
        g.w = bet0 * a.w + bet1 * b.w;
        *(float4*)(glds + r * 128 + c4 * 4) = g;
    }
    __syncthreads();
    const int rg = t >> 5, ct = t & 31;
    float acc[4][2];
    {
        float2 bv = *(const float2*)(bl + ct * 2);
        #pragma unroll
        for (int rr = 0; rr < 4; ++rr) { acc[rr][0] = bv.x; acc[rr][1] = bv.y; }
    }
    #pragma unroll 2
    for (int i = 0; i < 128; i += 4) {
        float4 xv[4];
        #pragma unroll
        for (int rr = 0; rr < 4; ++rr) xv[rr] = *(const float4*)(glds + (rg + 8 * rr) * 128 + i);
        #pragma unroll
        for (int qq = 0; qq < 4; ++qq) {
            float2 wv = *(const float2*)(wlds + (i + qq) * 64 + ct * 2);
            #pragma unroll
            for (int rr = 0; rr < 4; ++rr) {
                float xs = ((const float*)&xv[rr])[qq];
                acc[rr][0] = fmaf(xs, wv.x, acc[rr][0]);
                acc[rr][1] = fmaf(xs, wv.y, acc[rr][1]);
            }
        }
    }
    #pragma unroll
    for (int rr = 0; rr < 4; ++rr) {
        int grow = row0 + rg + 8 * rr;
        if (grow < N)
            *(float2*)(outp + (size_t)grow * 64 + ct * 2) = make_float2(acc[rr][0], acc[rr][1]);
    }
}

extern "C" void kernel_launch(void* const* d_in, const int* in_sizes, int n_in,
                              void* d_out, int out_size, void* d_ws, size_t ws_size,
                              hipStream_t stream) {
    (void)n_in; (void)out_size; (void)ws_size;
    const float* x_gene = (const float*)d_in[0];
    const float* x_dis  = (const float*)d_in[1];
    const int* eg_src   = (const int*)d_in[2];
    const int* eg_dst   = (const int*)d_in[3];
    const int* edg_src  = (const int*)d_in[4];
    const int* edg_dst  = (const int*)d_in[5];
    const float* W_gene = (const float*)d_in[6];
    const float* b_gene = (const float*)d_in[7];
    const float* W_dis  = (const float*)d_in[8];
    const float* b_dis  = (const float*)d_in[9];
    const float* att_src_gg = (const float*)d_in[10];
    const float* att_dst_gg = (const float*)d_in[11];
    const float* att_src_dg = (const float*)d_in[12];
    const float* att_dst_dg = (const float*)d_in[13];
    const float* Wk    = (const float*)d_in[14];
    const float* bk    = (const float*)d_in[15];
    const float* q     = (const float*)d_in[16];
    const float* W_lin = (const float*)d_in[17];
    const float* b_lin = (const float*)d_in[18];
    float* out = (float*)d_out;

    const int NG_ = in_sizes[0] / 128;
    const int ND_ = in_sizes[1] / 128;
    const int EG_ = in_sizes[2];
    const int EDG_ = in_sizes[4];

    char* w = (char*)d_ws;
    auto alloc = [&](size_t bytes) -> char* {
        char* p = w;
        w += (bytes + 255) & ~(size_t)255;
        return p;
    };
    unsigned short* hg = (unsigned short*)alloc((size_t)NG_ * 128 * 2);  // bf16
    unsigned short* hd = (unsigned short*)alloc((size_t)ND_ * 128 * 2);  // bf16
    float* e_src_gg = (float*)alloc((size_t)NG_ * 8 * 4);
    float* e_dst_gg = (float*)alloc((size_t)NG_ * 8 * 4);
    float* e_dst_dg = (float*)alloc((size_t)NG_ * 8 * 4);
    float* e_src_dg = (float*)alloc((size_t)ND_ * 8 * 4);
    float* out_gg   = (float*)alloc((size_t)NG_ * 128 * 4);
    float* out_dg   = (float*)alloc((size_t)NG_ * 128 * 4);
    int* offg  = (int*)alloc((size_t)(NG_ + 1) * 4);
    int* offd  = (int*)alloc((size_t)(NG_ + 1) * 4);
    int* srcs_g = (int*)alloc((size_t)EG_ * 4);
    int* srcs_d = (int*)alloc((size_t)EDG_ * 4);
    unsigned* coarse = (unsigned*)alloc((size_t)(EG_ + EDG_) * 4);
    int* bucketCnt    = (int*)alloc(4096);
    int* bucketBase   = (int*)alloc(4096);
    int* bucketCursor = (int*)alloc(4096);
    unsigned short* WkT   = (unsigned short*)alloc(128 * 128 * 2);
    unsigned short* bextg = (unsigned short*)alloc(160 * 128 * 2);
    unsigned short* bextd = (unsigned short*)alloc(160 * 128 * 2);
    float* beg = (float*)alloc(128);
    float* bed = (float*)alloc(128);
    float* score = (float*)alloc(1024);

    const int NBg = (NG_ + 255) >> BSHIFT;   // 391 for NG=100000
    const int NBtot = 2 * NBg;               // 782 <= 1024 (single-block scan) and <= 800 (LDS arrays)
    const int Etot = EG_ + EDG_;
    const int nbE = (Etot + 4095) / 4096;

    // 0. build extended B matrices (W | W@P folded e-dots) + WkT
    bext_kernel<<<1, 256, 0, stream>>>(W_gene, b_gene,
        att_src_gg, att_dst_gg, att_dst_dg, bextg, beg);
    bext_kernel<<<1, 256, 0, stream>>>(W_dis, b_dis,
        att_src_dg, (const float*)nullptr, (const float*)nullptr, bextd, bed);
    wkt_kernel<<<1, 128, 0, stream>>>(Wk, WkT);

    // 1. projections via MFMA (h bf16 + fused e-dots)
    proj_mfma<<<(NG_ + 127) / 128, 256, 0, stream>>>(
        x_gene, bextg, b_gene, beg, hg, e_src_gg, e_dst_gg, e_dst_dg, NG_);
    proj_mfma<<<(ND_ + 127) / 128, 256, 0, stream>>>(
        x_dis, bextd, b_dis, bed, hd, e_src_dg, (float*)nullptr, (float*)nullptr, ND_);

    // 2. two-level bucket CSR build (both graphs)
    hipMemsetAsync(bucketCnt, 0, (size_t)NBtot * 4, stream);
    bucket_hist<<<nbE, 256, 0, stream>>>(eg_dst, EG_, edg_dst, EDG_, NBg, NBtot, bucketCnt);
    bucket_scan<<<1, 1024, 0, stream>>>(bucketCnt, NBtot, Etot, bucketBase, bucketCursor);
    bucket_scatter<<<nbE, 256, 0, stream>>>(
        eg_dst, eg_src, EG_, edg_dst, edg_src, EDG_, NBg, NBtot, bucketCursor, coarse);
    bucket_sort<<<NBtot, 256, 0, stream>>>(
        coarse, bucketBase, NBg, EG_, EDG_, NG_, offg, offd, srcs_g, srcs_d);

    // 3. aggregates (bf16 gather, f32 accumulate, no-max softmax)
    aggregate_kernel<<<(NG_ + 3) / 4, 256, 0, stream>>>(
        hg, e_src_gg, e_dst_gg, offg, srcs_g, out_gg, NG_);
    aggregate_kernel<<<(NG_ + 3) / 4, 256, 0, stream>>>(
        hd, e_src_dg, e_dst_dg, offd, srcs_d, out_dg, NG_);

    // 4. semantic attention scores via bf16 MFMA + beta
    hipMemsetAsync(score, 0, 512, stream);
    score2_mfma<<<(NG_ + 63) / 64, 256, 0, stream>>>(out_gg, out_dg, WkT, bk, q, score, NG_);
    beta_kernel<<<1, 64, 0, stream>>>(score, 1.0f / (float)NG_);

    // 5. blend + final linear
    final_kernel<<<(NG_ + 31) / 32, 256, 0, stream>>>(
        out_gg, out_dg, score + 128, W_lin, b_lin, out, NG_);
}

// Round 18
// 377.349 us; speedup vs baseline: 1.0954x; 1.0954x over previous
//
#include <hip/hip_runtime.h>
#include <cstdint>
#include <cstddef>

#define NEG_SLOPE 0.2f
#define BSHIFT 8          // coarse bucket = dst >> 8 (256 dst nodes / bucket)

typedef __attribute__((ext_vector_type(8))) short short8;   // 8 bf16 = 4 VGPR (MFMA A/B frag)
typedef __attribute__((ext_vector_type(4))) float f32x4;    // MFMA C/D frag

__device__ __forceinline__ float leakyf(float x) { return x > 0.f ? x : NEG_SLOPE * x; }
__device__ __forceinline__ float fast_tanh(float x) {
    float e = __expf(2.f * x);
    return 1.f - 2.f / (e + 1.f);
}
__device__ __forceinline__ unsigned short f2bf(float x) {   // f32 -> bf16 RNE
    unsigned u = __float_as_uint(x);
    unsigned r = u + 0x7FFFu + ((u >> 16) & 1u);
    return (unsigned short)(r >> 16);
}

// ---------------- projection (x@W+b) + per-head attention dots ----------------
// round-16 proven: f32 FMA, 32-row tile, 4x4 acc, 16-K-row (8KB) W chunks; h stored bf16.
// (round-17 MFMA version reverted: 782-block grid + store-heavy epilogue = latency-bound,
// 74us, no better than f32; plus 35us single-block setup kernels.)
__global__ __launch_bounds__(256) void proj_kernel(
    const float* __restrict__ x, const float* __restrict__ W, const float* __restrict__ bias,
    unsigned short* __restrict__ hout, int N,
    const float* __restrict__ att0, float* __restrict__ e0,
    const float* __restrict__ att1, float* __restrict__ e1,
    const float* __restrict__ att2, float* __restrict__ e2)
{
    __shared__ float xlds[32 * 128];  // 16 KB: x tile
    __shared__ float wlds[16 * 128];  // 8 KB: W K-chunk
    const int t = threadIdx.x;
    const int row0 = blockIdx.x * 32;
    #pragma unroll
    for (int p = 0; p < 4; ++p) {
        int idx = t + 256 * p;
        int r = idx >> 5;
        int c4 = idx & 31;
        float4 v = make_float4(0.f, 0.f, 0.f, 0.f);
        if (row0 + r < N) v = *(const float4*)(x + (size_t)(row0 + r) * 128 + c4 * 4);
        *(float4*)(xlds + r * 128 + c4 * 4) = v;
    }
    const int rg = t >> 5, ct = t & 31;
    float acc[4][4];
    {
        float4 bv = *(const float4*)(bias + ct * 4);
        #pragma unroll
        for (int rr = 0; rr < 4; ++rr) {
            acc[rr][0] = bv.x; acc[rr][1] = bv.y; acc[rr][2] = bv.z; acc[rr][3] = bv.w;
        }
    }
    for (int kc = 0; kc < 8; ++kc) {
        __syncthreads();  // kc=0: x staged; kc>0: previous chunk's compute done (WAR on wlds)
        #pragma unroll
        for (int p = 0; p < 2; ++p) {
            int idx = t + 256 * p;
            *(float4*)(wlds + idx * 4) = *(const float4*)(W + (size_t)kc * 2048 + idx * 4);
        }
        __syncthreads();
        #pragma unroll 2
        for (int i2 = 0; i2 < 16; i2 += 4) {
            const int i = kc * 16 + i2;
            float4 xv[4];
            #pragma unroll
            for (int rr = 0; rr < 4; ++rr) xv[rr] = *(const float4*)(xlds + (rg + 8 * rr) * 128 + i);
            #pragma unroll
            for (int qq = 0; qq < 4; ++qq) {
                float4 wv = *(const float4*)(wlds + (i2 + qq) * 128 + ct * 4);
                #pragma unroll
                for (int rr = 0; rr < 4; ++rr) {
                    float xs = ((const float*)&xv[rr])[qq];
                    acc[rr][0] = fmaf(xs, wv.x, acc[rr][0]);
                    acc[rr][1] = fmaf(xs, wv.y, acc[rr][1]);
                    acc[rr][2] = fmaf(xs, wv.z, acc[rr][2]);
                    acc[rr][3] = fmaf(xs, wv.w, acc[rr][3]);
                }
            }
        }
    }
    // store h as bf16 (4 cols -> int2)
    #pragma unroll
    for (int rr = 0; rr < 4; ++rr) {
        int grow = row0 + rg + 8 * rr;
        if (grow < N) {
            int2 u;
            u.x = (int)f2bf(acc[rr][0]) | ((int)f2bf(acc[rr][1]) << 16);
            u.y = (int)f2bf(acc[rr][2]) | ((int)f2bf(acc[rr][3]) << 16);
            *(int2*)(hout + (size_t)grow * 128 + ct * 4) = u;
        }
    }
    // e-dots: thread's 4 cols are inside head (ct>>2); reduce over 4-lane col group
    const int head = ct >> 2;
    const bool wlane = (ct & 3) == 0;
    if (att0) {
        float4 av = *(const float4*)(att0 + ct * 4);
        #pragma unroll
        for (int rr = 0; rr < 4; ++rr) {
            float p_ = acc[rr][0] * av.x + acc[rr][1] * av.y + acc[rr][2] * av.z + acc[rr][3] * av.w;
            p_ += __shfl_xor(p_, 1);
            p_ += __shfl_xor(p_, 2);
            int grow = row0 + rg + 8 * rr;
            if (wlane && grow < N) e0[(size_t)grow * 8 + head] = p_;
        }
    }
    if (att1) {
        float4 av = *(const float4*)(att1 + ct * 4);
        #pragma unroll
        for (int rr = 0; rr < 4; ++rr) {
            float p_ = acc[rr][0] * av.x + acc[rr][1] * av.y + acc[rr][2] * av.z + acc[rr][3] * av.w;
            p_ += __shfl_xor(p_, 1);
            p_ += __shfl_xor(p_, 2);
            int grow = row0 + rg + 8 * rr;
            if (wlane && grow < N) e1[(size_t)grow * 8 + head] = p_;
        }
    }
    if (att2) {
        float4 av = *(const float4*)(att2 + ct * 4);
        #pragma unroll
        for (int rr = 0; rr < 4; ++rr) {
            float p_ = acc[rr][0] * av.x + acc[rr][1] * av.y + acc[rr][2] * av.z + acc[rr][3] * av.w;
            p_ += __shfl_xor(p_, 1);
            p_ += __shfl_xor(p_, 2);
            int grow = row0 + rg + 8 * rr;
            if (wlane && grow < N) e2[(size_t)grow * 8 + head] = p_;
        }
    }
}

// ================= two-level bucket CSR build =================
__global__ __launch_bounds__(256) void bucket_hist(
    const int* __restrict__ dstg, int Eg, const int* __restrict__ dstd, int Ed,
    int NBg, int NBtot, int* __restrict__ bucketCnt)
{
    __shared__ int h[1024];
    const int t = threadIdx.x;
    for (int j = t; j < NBtot; j += 256) h[j] = 0;
    __syncthreads();
    const int Etot = Eg + Ed;
    const int base = blockIdx.x * 4096;
    #pragma unroll
    for (int k = 0; k < 16; ++k) {
        int i = base + k * 256 + t;
        if (i < Etot) {
            int b = (i < Eg) ? (dstg[i] >> BSHIFT) : NBg + (dstd[i - Eg] >> BSHIFT);
            atomicAdd(&h[b], 1);
        }
    }
    __syncthreads();
    for (int j = t; j < NBtot; j += 256) {
        int c = h[j];
        if (c) atomicAdd(&bucketCnt[j], c);
    }
}

__global__ void bucket_scan(const int* __restrict__ bucketCnt, int NBtot, int Etot,
                            int* __restrict__ bucketBase, int* __restrict__ bucketCursor)
{
    __shared__ int s[1024];
    int t = threadIdx.x;
    int v = (t < NBtot) ? bucketCnt[t] : 0;
    s[t] = v;
    __syncthreads();
    for (int o = 1; o < 1024; o <<= 1) {
        int add = (t >= o) ? s[t - o] : 0;
        __syncthreads();
        s[t] += add;
        __syncthreads();
    }
    if (t < NBtot) {
        int e = s[t] - v;
        bucketBase[t] = e;
        bucketCursor[t] = e;
    }
    if (t == 0) bucketBase[NBtot] = Etot;
}

__global__ __launch_bounds__(256) void bucket_scatter(
    const int* __restrict__ dstg, const int* __restrict__ srcg, int Eg,
    const int* __restrict__ dstd, const int* __restrict__ srcd, int Ed,
    int NBg, int NBtot, int* __restrict__ bucketCursor, unsigned* __restrict__ coarse)
{
    __shared__ int h[800];
    __shared__ int basearr[800];
    __shared__ int cur[800];
    const int t = threadIdx.x;
    for (int j = t; j < NBtot; j += 256) h[j] = 0;
    __syncthreads();
    const int Etot = Eg + Ed;
    const int base = blockIdx.x * 4096;
    int bk[16];
    unsigned pk[16];
    #pragma unroll
    for (int k = 0; k < 16; ++k) {
        int i = base + k * 256 + t;
        bk[k] = -1;
        if (i < Etot) {
            int dst, src, goff;
            if (i < Eg) { dst = dstg[i]; src = srcg[i]; goff = 0; }
            else        { dst = dstd[i - Eg]; src = srcd[i - Eg]; goff = NBg; }
            bk[k] = goff + (dst >> BSHIFT);
            pk[k] = (unsigned)src | ((unsigned)(dst & 255) << 24);
            atomicAdd(&h[bk[k]], 1);
        }
    }
    __syncthreads();
    for (int j = t; j < NBtot; j += 256) {
        int c = h[j];
        basearr[j] = c ? atomicAdd(&bucketCursor[j], c) : 0;
        cur[j] = 0;
    }
    __syncthreads();
    #pragma unroll
    for (int k = 0; k < 16; ++k) {
        if (bk[k] >= 0) {
            int r = atomicAdd(&cur[bk[k]], 1);
            coarse[basearr[bk[k]] + r] = pk[k];
        }
    }
}

__global__ __launch_bounds__(256) void bucket_sort(
    const unsigned* __restrict__ coarse, const int* __restrict__ bucketBase,
    int NBg, int Eg, int Ed, int N,
    int* __restrict__ offg, int* __restrict__ offd,
    int* __restrict__ srcs_g, int* __restrict__ srcs_d)
{
    __shared__ int hist[256];
    __shared__ int excl[256];
    __shared__ int cur[256];
    const int b = blockIdx.x;
    const int t = threadIdx.x;
    const int s0 = bucketBase[b], s1 = bucketBase[b + 1];
    const int cnt = s1 - s0;
    const bool isg = b < NBg;
    const int d0 = (isg ? b : b - NBg) << BSHIFT;
    hist[t] = 0;
    __syncthreads();
    for (int i = t; i < cnt; i += 256) {
        unsigned p = coarse[s0 + i];
        atomicAdd(&hist[p >> 24], 1);
    }
    __syncthreads();
    int v = hist[t];
    excl[t] = v;
    __syncthreads();
    for (int o = 1; o < 256; o <<= 1) {
        int add = (t >= o) ? excl[t - o] : 0;
        __syncthreads();
        excl[t] += add;
        __syncthreads();
    }
    const int e = excl[t] - v;  // exclusive prefix within bucket
    const int localBase = isg ? s0 : s0 - Eg;
    const int d = d0 + t;
    if (d < N) {
        if (isg) offg[d] = localBase + e;
        else     offd[d] = localBase + e;
    }
    cur[t] = e;
    __syncthreads();
    int* outp = isg ? srcs_g : srcs_d;
    for (int i = t; i < cnt; i += 256) {
        unsigned p = coarse[s0 + i];
        int r = atomicAdd(&cur[p >> 24], 1);
        outp[localBase + r] = (int)(p & 0xFFFFFFu);
    }
    if (b == 0 && t == 0) { offg[N] = Eg; offd[N] = Ed; }
}

// ---------------- fused per-dst-node softmax aggregation (both graphs, 1 dispatch) ----
// Blocks [0,nbA) process graph A (gene-gene), [nbA,..) graph B (disease-gene).
// xs BF16; f32 accumulate; no-max softmax (logits bounded ~3, shift-invariant).
__global__ __launch_bounds__(256) void aggregate2_kernel(
    const unsigned short* __restrict__ xsA, const float* __restrict__ esrcA,
    const float* __restrict__ edstA, const int* __restrict__ offA,
    const int* __restrict__ srcA, float* __restrict__ outA,
    const unsigned short* __restrict__ xsB, const float* __restrict__ esrcB,
    const float* __restrict__ edstB, const int* __restrict__ offB,
    const int* __restrict__ srcB, float* __restrict__ outB,
    int Nd, int nbA)
{
    __shared__ float exbuf[4][64 * 8];
    const int lane = threadIdx.x & 63;
    const int wslot = threadIdx.x >> 6;
    const bool isA = blockIdx.x < nbA;
    const int blk = isA ? blockIdx.x : blockIdx.x - nbA;
    const unsigned short* xs = isA ? xsA : xsB;
    const float* esrc = isA ? esrcA : esrcB;
    const float* edst = isA ? edstA : edstB;
    const int* off = isA ? offA : offB;
    const int* srcsorted = isA ? srcA : srcB;
    float* outp = isA ? outA : outB;
    const int n = blk * 4 + wslot;
    if (n >= Nd) return;
    const int o0 = off[n], o1 = off[n + 1];
    const int deg = o1 - o0;
    const int li = lane & 31, half = lane >> 5;
    const int j0 = li * 4;       // this lane's 4 cols (within its half)
    const int hh = li >> 2;      // head owning those cols
    if (deg == 0) {
        if (half == 0) *(float4*)(outp + (size_t)n * 128 + j0) = make_float4(0.f, 0.f, 0.f, 0.f);
        return;
    }
    float ed[8];
    {
        float4 a = *(const float4*)(edst + (size_t)n * 8);
        float4 b = *(const float4*)(edst + (size_t)n * 8 + 4);
        ed[0] = a.x; ed[1] = a.y; ed[2] = a.z; ed[3] = a.w;
        ed[4] = b.x; ed[5] = b.y; ed[6] = b.z; ed[7] = b.w;
    }
    if (deg <= 64) {
        const bool act = lane < deg;
        int s = act ? srcsorted[o0 + lane] : 0;   // coalesced
        float exv[8];
        {
            float4 ea = make_float4(0.f, 0.f, 0.f, 0.f), eb = ea;
            if (act) {
                ea = *(const float4*)(esrc + (size_t)s * 8);
                eb = *(const float4*)(esrc + (size_t)s * 8 + 4);
            }
            float a[8] = {ea.x, ea.y, ea.z, ea.w, eb.x, eb.y, eb.z, eb.w};
            #pragma unroll
            for (int h2 = 0; h2 < 8; ++h2)
                exv[h2] = act ? __expf(leakyf(a[h2] + ed[h2])) : 0.f;
        }
        *(float4*)(&exbuf[wslot][lane * 8])     = make_float4(exv[0], exv[1], exv[2], exv[3]);
        *(float4*)(&exbuf[wslot][lane * 8 + 4]) = make_float4(exv[4], exv[5], exv[6], exv[7]);
        float4 num = make_float4(0.f, 0.f, 0.f, 0.f);
        float den = 0.f;
        const int iters = (deg + 1) >> 1;
        #pragma unroll 2
        for (int k = 0; k < iters; ++k) {
            int i = 2 * k + half;
            if (i < deg) {
                int si = __shfl(s, i);
                float wgt = exbuf[wslot][i * 8 + hh];
                int2 xv2 = *(const int2*)(xs + (size_t)si * 128 + j0);
                unsigned ux = (unsigned)xv2.x, uy = (unsigned)xv2.y;
                float x0 = __uint_as_float(ux << 16);
                float x1 = __uint_as_float(ux & 0xFFFF0000u);
                float x2 = __uint_as_float(uy << 16);
                float x3 = __uint_as_float(uy & 0xFFFF0000u);
                num.x = fmaf(wgt, x0, num.x);
                num.y = fmaf(wgt, x1, num.y);
                num.z = fmaf(wgt, x2, num.z);
                num.w = fmaf(wgt, x3, num.w);
                den += wgt;
            }
        }
        num.x += __shfl_xor(num.x, 32);
        num.y += __shfl_xor(num.y, 32);
        num.z += __shfl_xor(num.z, 32);
        num.w += __shfl_xor(num.w, 32);
        den += __shfl_xor(den, 32);
        if (half == 0) {
            float inv = 1.f / (den + 1e-16f);
            float4 r;
            r.x = fmaxf(num.x * inv, 0.f);
            r.y = fmaxf(num.y * inv, 0.f);
            r.z = fmaxf(num.z * inv, 0.f);
            r.w = fmaxf(num.w * inv, 0.f);
            *(float4*)(outp + (size_t)n * 128 + j0) = r;
        }
        return;
    }
    // ---- slow path (deg > 64), no-max version ----
    {
        const int j0b = lane * 2;
        const int h = lane >> 3;
        float edh;
        {
            float u4a = (h & 4) ? ed[4] : ed[0];
            float u4b = (h & 4) ? ed[5] : ed[1];
            float u4c = (h & 4) ? ed[6] : ed[2];
            float u4d = (h & 4) ? ed[7] : ed[3];
            float u2a = (h & 2) ? u4c : u4a;
            float u2b = (h & 2) ? u4d : u4b;
            edh = (h & 1) ? u2b : u2a;
        }
        float den = 0.f, num0 = 0.f, num1 = 0.f;
        for (int base = 0; base < deg; base += 64) {
            int ii = base + lane;
            bool act = ii < deg;
            int sreg = srcsorted[o0 + (act ? ii : 0)];
            int cl = deg - base;
            if (cl > 64) cl = 64;
            for (int i = 0; i < cl; ++i) {
                int s = __shfl(sreg, i);
                float ev = esrc[(size_t)s * 8 + h];
                float ex = __expf(leakyf(ev + edh));
                unsigned uv = *(const unsigned*)(xs + (size_t)s * 128 + j0b);
                float x0 = __uint_as_float(uv << 16);
                float x1 = __uint_as_float(uv & 0xFFFF0000u);
                num0 = fmaf(ex, x0, num0);
                num1 = fmaf(ex, x1, num1);
                den += ex;
            }
        }
        float inv = 1.f / (den + 1e-16f);
        float r0 = num0 * inv, r1 = num1 * inv;
        r0 = r0 > 0.f ? r0 : 0.f;
        r1 = r1 > 0.f ? r1 : 0.f;
        *(float2*)(outp + (size_t)n * 128 + j0b) = make_float2(r0, r1);
    }
}

// ---------------- Wk transpose + bf16 convert (one-time per launch) ----------------
__global__ void wkt_kernel(const float* __restrict__ Wk, unsigned short* __restrict__ WkT) {
    int c = threadIdx.x;  // 128 threads = one column each
    for (int k = 0; k < 128; ++k)
        WkT[c * 128 + k] = f2bf(Wk[(size_t)k * 128 + c]);
}

// ---------------- semantic attention scores via bf16 MFMA ----------------
// 128-row tile (rows 0-63 = gg[row0..+63], 64-127 = dg same range), 4 waves; wave w owns
// rows [32w, 32w+32) as TWO 16-row A-frags -> each B-frag load feeds 2 MFMAs.
// A from XOR-swizzled LDS bf16 tile; B from L2-resident WkT.
// C layout (verified): col = lane&15, row = (lane>>4)*4 + reg.
__global__ __launch_bounds__(256) void score2_mfma(
    const float* __restrict__ gg, const float* __restrict__ dg,
    const unsigned short* __restrict__ WkT,
    const float* __restrict__ bk, const float* __restrict__ q,
    float* __restrict__ scoreAcc, int N)
{
    __shared__ short atile[128 * 128];  // 32 KB bf16, 16B-chunk XOR-swizzled
    __shared__ float sred[4];
    const int t = threadIdx.x;
    const int row0 = blockIdx.x * 64;
    {
        const int row = t >> 1, q8 = t & 1;
        const int gr = row0 + (row & 63);
        const float* srcp = (row < 64) ? gg : dg;
        #pragma unroll
        for (int c = 0; c < 8; ++c) {
            const int kc = q8 * 8 + c;
            float4 l0 = make_float4(0.f, 0.f, 0.f, 0.f), l1 = l0;
            if (gr < N) {
                l0 = *(const float4*)(srcp + (size_t)gr * 128 + kc * 8);
                l1 = *(const float4*)(srcp + (size_t)gr * 128 + kc * 8 + 4);
            }
            int4 u;
            u.x = (int)f2bf(l0.x) | ((int)f2bf(l0.y) << 16);
            u.y = (int)f2bf(l0.z) | ((int)f2bf(l0.w) << 16);
            u.z = (int)f2bf(l1.x) | ((int)f2bf(l1.y) << 16);
            u.w = (int)f2bf(l1.z) | ((int)f2bf(l1.w) << 16);
            const int chunk = row * 16 + kc;
            const int chunk_sw = chunk ^ (row & 7);
            *(int4*)((char*)atile + chunk_sw * 16) = u;
        }
    }
    __syncthreads();
    const int w = t >> 6, l = t & 63;
    const int lrow = l & 15, lk = l >> 4;
    f32x4 acc[2][8];
    #pragma unroll
    for (int a = 0; a < 2; ++a)
        #pragma unroll
        for (int ct = 0; ct < 8; ++ct) { acc[a][ct][0] = 0.f; acc[a][ct][1] = 0.f; acc[a][ct][2] = 0.f; acc[a][ct][3] = 0.f; }
    #pragma unroll
    for (int ks = 0; ks < 4; ++ks) {
        short8 afr[2];
        #pragma unroll
        for (int a = 0; a < 2; ++a) {
            const int rowl = w * 32 + a * 16 + lrow;
            const int chunk = rowl * 16 + ks * 4 + lk;
            const int chunk_sw = chunk ^ (rowl & 7);
            afr[a] = *(short8*)((char*)atile + chunk_sw * 16);
        }
        #pragma unroll
        for (int ct = 0; ct < 8; ++ct) {
            const unsigned short* bp = WkT + ((size_t)(ct * 16 + lrow) * 128 + ks * 32 + lk * 8);
            short8 bfr = *(const short8*)bp;
            acc[0][ct] = __builtin_amdgcn_mfma_f32_16x16x32_bf16(afr[0], bfr, acc[0][ct], 0, 0, 0);
            acc[1][ct] = __builtin_amdgcn_mfma_f32_16x16x32_bf16(afr[1], bfr, acc[1][ct], 0, 0, 0);
        }
    }
    float s = 0.f;
    #pragma unroll
    for (int ct = 0; ct < 8; ++ct) {
        const int col = ct * 16 + lrow;
        const float bkv = bk[col];
        const float qv = q[col];
        #pragma unroll
        for (int a = 0; a < 2; ++a) {
            #pragma unroll
            for (int r = 0; r < 4; ++r) {
                const int rloc = a * 16 + lk * 4 + r;
                const int grow = row0 + ((w * 32 + rloc) & 63);
                if (grow < N) s = fmaf(fast_tanh(acc[a][ct][r] + bkv), qv, s);
            }
        }
    }
    #pragma unroll
    for (int o = 1; o < 64; o <<= 1) s += __shfl_xor(s, o);
    if (l == 0) sred[w] = s;
    __syncthreads();
    if (t == 0) {
        float pg = sred[0] + sred[1];   // waves 0,1 = gg rows
        float pd = sred[2] + sred[3];   // waves 2,3 = dg rows
        int slot = blockIdx.x & 63;
        atomicAdd(&scoreAcc[slot], pg);
        atomicAdd(&scoreAcc[64 + slot], pd);
    }
}

// ---------------- tiny: reduce 2x64 score slots -> softmax betas ----------------
__global__ void beta_kernel(float* __restrict__ scoreAcc, float invN) {
    int t = threadIdx.x;  // 64 threads
    float v0 = scoreAcc[t];
    float v1 = scoreAcc[64 + t];
    #pragma unroll
    for (int o = 1; o < 64; o <<= 1) {
        v0 += __shfl_xor(v0, o);
        v1 += __shfl_xor(v1, o);
    }
    if (t == 0) {
        float s0 = v0 * invN, s1 = v1 * invN;
        float mx = fmaxf(s0, s1);
        float e0 = __expf(s0 - mx), e1 = __expf(s1 - mx);
        float inv = 1.f / (e0 + e1);
        scoreAcc[128] = e0 * inv;
        scoreAcc[129] = e1 * inv;
    }
}

// ---------------- final: beta blend + @W_lin + b_lin (W_lin staged in LDS) ----------------
__global__ __launch_bounds__(256) void final_kernel(
    const float* __restrict__ gg, const float* __restrict__ dg,
    const float* __restrict__ beta,   // scoreAcc+128: {beta0, beta1}
    const float* __restrict__ Wl, const float* __restrict__ bl,
    float* __restrict__ outp, int N)
{
    __shared__ float wlds[128 * 64];  // 32 KB — whole W_lin
    __shared__ float glds[32 * 128];  // 16 KB — blended tile
    const int t = threadIdx.x;
    #pragma unroll
    for (int p = 0; p < 8; ++p) {
        int idx = (t + 256 * p) * 4;
        *(float4*)(wlds + idx) = *(const float4*)(Wl + idx);
    }
    const float bet0 = beta[0], bet1 = beta[1];
    const int row0 = blockIdx.x * 32;
    #pragma unroll
    for (int p = 0; p < 4; ++p) {
        int idx = t + 256 * p;
        int r = idx >> 5;
        int c4 = idx & 31;
        float4 a = make_float4(0.f, 0.f, 0.f, 0.f), b = a, g;
        if (row0 + r < N) {
            a = *(const float4*)(gg + (size_t)(row0 + r) * 128 + c4 * 4);
            b = *(const float4*)(dg + (size_t)(row0 + r) * 128 + c4 * 4);
        }
        g.x = bet0 * a.x + bet1 * b.x;
        g.y = bet0 * a.y + bet1 * b.y;
        g.z = bet0 * a.z + bet1 * b.z;
        g.w = bet0 * a.w + bet1 * b.w;
        *(float4*)(glds + r * 128 + c4 * 4) = g;
    }
    __syncthreads();
    const int rg = t >> 5, ct = t & 31;
    float acc[4][2];
    {
        float2 bv = *(const float2*)(bl + ct * 2);
        #pragma unroll
        for (int rr = 0; rr < 4; ++rr) { acc[rr][0] = bv.x; acc[rr][1] = bv.y; }
    }
    #pragma unroll 2
    for (int i = 0; i < 128; i += 4) {
        float4 xv[4];
        #pragma unroll
        for (int rr = 0; rr < 4; ++rr) xv[rr] = *(const float4*)(glds + (rg + 8 * rr) * 128 + i);
        #pragma unroll
        for (int qq = 0; qq < 4; ++qq) {
            float2 wv = *(const float2*)(wlds + (i + qq) * 64 + ct * 2);
            #pragma unroll
            for (int rr = 0; rr < 4; ++rr) {
                float xs = ((const float*)&xv[rr])[qq];
                acc[rr][0] = fmaf(xs, wv.x, acc[rr][0]);
                acc[rr][1] = fmaf(xs, wv.y, acc[rr][1]);
            }
        }
    }
    #pragma unroll
    for (int rr = 0; rr < 4; ++rr) {
        int grow = row0 + rg + 8 * rr;
        if (grow < N)
            *(float2*)(outp + (size_t)grow * 64 + ct * 2) = make_float2(acc[rr][0], acc[rr][1]);
    }
}

extern "C" void kernel_launch(void* const* d_in, const int* in_sizes, int n_in,
                              void* d_out, int out_size, void* d_ws, size_t ws_size,
                              hipStream_t stream) {
    (void)n_in; (void)out_size; (void)ws_size;
    const float* x_gene = (const float*)d_in[0];
    const float* x_dis  = (const float*)d_in[1];
    const int* eg_src   = (const int*)d_in[2];
    const int* eg_dst   = (const int*)d_in[3];
    const int* edg_src  = (const int*)d_in[4];
    const int* edg_dst  = (const int*)d_in[5];
    const float* W_gene = (const float*)d_in[6];
    const float* b_gene = (const float*)d_in[7];
    const float* W_dis  = (const float*)d_in[8];
    const float* b_dis  = (const float*)d_in[9];
    const float* att_src_gg = (const float*)d_in[10];
    const float* att_dst_gg = (const float*)d_in[11];
    const float* att_src_dg = (const float*)d_in[12];
    const float* att_dst_dg = (const float*)d_in[13];
    const float* Wk    = (const float*)d_in[14];
    const float* bk    = (const float*)d_in[15];
    const float* q     = (const float*)d_in[16];
    const float* W_lin = (const float*)d_in[17];
    const float* b_lin = (const float*)d_in[18];
    float* out = (float*)d_out;

    const int NG_ = in_sizes[0] / 128;
    const int ND_ = in_sizes[1] / 128;
    const int EG_ = in_sizes[2];
    const int EDG_ = in_sizes[4];

    char* w = (char*)d_ws;
    auto alloc = [&](size_t bytes) -> char* {
        char* p = w;
        w += (bytes + 255) & ~(size_t)255;
        return p;
    };
    unsigned short* hg = (unsigned short*)alloc((size_t)NG_ * 128 * 2);  // bf16
    unsigned short* hd = (unsigned short*)alloc((size_t)ND_ * 128 * 2);  // bf16
    float* e_src_gg = (float*)alloc((size_t)NG_ * 8 * 4);
    float* e_dst_gg = (float*)alloc((size_t)NG_ * 8 * 4);
    float* e_dst_dg = (float*)alloc((size_t)NG_ * 8 * 4);
    float* e_src_dg = (float*)alloc((size_t)ND_ * 8 * 4);
    float* out_gg   = (float*)alloc((size_t)NG_ * 128 * 4);
    float* out_dg   = (float*)alloc((size_t)NG_ * 128 * 4);
    int* offg  = (int*)alloc((size_t)(NG_ + 1) * 4);
    int* offd  = (int*)alloc((size_t)(NG_ + 1) * 4);
    int* srcs_g = (int*)alloc((size_t)EG_ * 4);
    int* srcs_d = (int*)alloc((size_t)EDG_ * 4);
    unsigned* coarse = (unsigned*)alloc((size_t)(EG_ + EDG_) * 4);
    int* bucketCnt    = (int*)alloc(4096);
    int* bucketBase   = (int*)alloc(4096);
    int* bucketCursor = (int*)alloc(4096);
    unsigned short* WkT = (unsigned short*)alloc(128 * 128 * 2);
    float* score = (float*)alloc(1024);

    const int NBg = (NG_ + 255) >> BSHIFT;   // 391 for NG=100000
    const int NBtot = 2 * NBg;               // 782 <= 1024 (single-block scan) and <= 800 (LDS arrays)
    const int Etot = EG_ + EDG_;
    const int nbE = (Etot + 4095) / 4096;

    // 1. projections (+ e-vectors); Wk transpose alongside
    proj_kernel<<<(NG_ + 31) / 32, 256, 0, stream>>>(
        x_gene, W_gene, b_gene, hg, NG_,
        att_src_gg, e_src_gg, att_dst_gg, e_dst_gg, att_dst_dg, e_dst_dg);
    proj_kernel<<<(ND_ + 31) / 32, 256, 0, stream>>>(
        x_dis, W_dis, b_dis, hd, ND_,
        att_src_dg, e_src_dg, (const float*)nullptr, (float*)nullptr,
        (const float*)nullptr, (float*)nullptr);
    wkt_kernel<<<1, 128, 0, stream>>>(Wk, WkT);

    // 2. two-level bucket CSR build (both graphs)
    hipMemsetAsync(bucketCnt, 0, (size_t)NBtot * 4, stream);
    bucket_hist<<<nbE, 256, 0, stream>>>(eg_dst, EG_, edg_dst, EDG_, NBg, NBtot, bucketCnt);
    bucket_scan<<<1, 1024, 0, stream>>>(bucketCnt, NBtot, Etot, bucketBase, bucketCursor);
    bucket_scatter<<<nbE, 256, 0, stream>>>(
        eg_dst, eg_src, EG_, edg_dst, edg_src, EDG_, NBg, NBtot, bucketCursor, coarse);
    bucket_sort<<<NBtot, 256, 0, stream>>>(
        coarse, bucketBase, NBg, EG_, EDG_, NG_, offg, offd, srcs_g, srcs_d);

    // 3. fused aggregates (both graphs, one dispatch; bf16 gather, no-max softmax)
    {
        const int nbA = (NG_ + 3) / 4;
        aggregate2_kernel<<<2 * nbA, 256, 0, stream>>>(
            hg, e_src_gg, e_dst_gg, offg, srcs_g, out_gg,
            hd, e_src_dg, e_dst_dg, offd, srcs_d, out_dg,
            NG_, nbA);
    }

    // 4. semantic attention scores via bf16 MFMA + beta
    hipMemsetAsync(score, 0, 512, stream);
    score2_mfma<<<(NG_ + 63) / 64, 256, 0, stream>>>(out_gg, out_dg, WkT, bk, q, score, NG_);
    beta_kernel<<<1, 64, 0, stream>>>(score, 1.0f / (float)NG_);

    // 5. blend + final linear
    final_kernel<<<(NG_ + 31) / 32, 256, 0, stream>>>(
        out_gg, out_dg, score + 128, W_lin, b_lin, out, NG_);
}

// Round 19
// 363.788 us; speedup vs baseline: 1.1363x; 1.0373x over previous
//
#include <hip/hip_runtime.h>
#include <cstdint>
#include <cstddef>

#define NEG_SLOPE 0.2f
#define BSHIFT 8          // coarse bucket = dst >> 8 (256 dst nodes / bucket)

typedef __attribute__((ext_vector_type(8))) short short8;   // 8 bf16 = 4 VGPR (MFMA A/B frag)
typedef __attribute__((ext_vector_type(4))) float f32x4;    // MFMA C/D frag

__device__ __forceinline__ float leakyf(float x) { return x > 0.f ? x : NEG_SLOPE * x; }
__device__ __forceinline__ float fast_tanh(float x) {
    float e = __expf(2.f * x);
    return 1.f - 2.f / (e + 1.f);
}
__device__ __forceinline__ unsigned short f2bf(float x) {   // f32 -> bf16 RNE
    unsigned u = __float_as_uint(x);
    unsigned r = u + 0x7FFFu + ((u >> 16) & 1u);
    return (unsigned short)(r >> 16);
}

// ---------------- build extended B matrix for proj MFMA (parallel: 20 blocks) --------
// BExt[col][k] (col-major, bf16), 160 cols: [0,128)=W; [128,136)=W@P(att0);
// [136,144)=W@P(att1); [144,152)=W@P(att2); [152,160)=0.  beArr[24] = bias@P.
// (math verified in round 17; round-17's single-block version was ~35us serial setup)
__global__ void bext2_kernel(const float* __restrict__ W, const float* __restrict__ bias,
                             const float* __restrict__ att0, const float* __restrict__ att1,
                             const float* __restrict__ att2,
                             unsigned short* __restrict__ BExt, float* __restrict__ beArr)
{
    const int t = threadIdx.x;
    const int cg = blockIdx.x;           // 0..19 -> cols [cg*8, cg*8+8)
    for (int task = t; task < 1024; task += 256) {
        int col = cg * 8 + (task >> 7);
        int k = task & 127;
        float v;
        if (col < 128) {
            v = W[(size_t)k * 128 + col];
        } else {
            int ec = col - 128, vec = ec >> 3, h = ec & 7;
            const float* att = (vec == 0) ? att0 : (vec == 1) ? att1 : (vec == 2) ? att2 : nullptr;
            v = 0.f;
            if (att) {
                #pragma unroll
                for (int d = 0; d < 16; ++d) v = fmaf(W[(size_t)k * 128 + h * 16 + d], att[h * 16 + d], v);
            }
        }
        BExt[(size_t)col * 128 + k] = f2bf(v);
    }
    if (cg == 0 && t < 24) {
        int vec = t >> 3, h = t & 7;
        const float* att = (vec == 0) ? att0 : (vec == 1) ? att1 : att2;
        float s = 0.f;
        if (att) {
            #pragma unroll
            for (int d = 0; d < 16; ++d) s = fmaf(bias[h * 16 + d], att[h * 16 + d], s);
        }
        beArr[t] = s;
    }
}

// ---------------- projection via bf16 MFMA, OPERAND-SWAPPED (one dispatch, both types) --
// mfma(W_frag as A, x_frag as B) -> D[m=W-col][n=x-row]: lane owns x-row = lane&15 and
// W-cols ct*16 + (lane>>4)*4 + r -> h-stores are packed int2 (4 bf16), e-stores 4 scalars.
// (fixes round-17's 64-scalar-store epilogue; merged grid 1173 blocks fixes starvation.)
// Blocks [0,nbG) = gene, rest = disease.
__global__ __launch_bounds__(256) void proj_mfma2(
    const float* __restrict__ xg, const unsigned short* __restrict__ bextg,
    const float* __restrict__ biasg, const float* __restrict__ beg,
    unsigned short* __restrict__ hgp, float* __restrict__ e0g, float* __restrict__ e1g,
    float* __restrict__ e2g, int NG, int nbG,
    const float* __restrict__ xd, const unsigned short* __restrict__ bextd,
    const float* __restrict__ biasd, const float* __restrict__ bed,
    unsigned short* __restrict__ hdp, float* __restrict__ e0d, int ND)
{
    __shared__ short atile[128 * 128];  // 32 KB bf16, 16B-chunk XOR-swizzled
    const int t = threadIdx.x;
    const bool isG = blockIdx.x < nbG;
    const int blk = isG ? blockIdx.x : blockIdx.x - nbG;
    const float* x = isG ? xg : xd;
    const unsigned short* BExt = isG ? bextg : bextd;
    const float* bias = isG ? biasg : biasd;
    const float* beArr = isG ? beg : bed;
    unsigned short* hout = isG ? hgp : hdp;
    float* e0 = isG ? e0g : e0d;
    float* e1 = isG ? e1g : (float*)nullptr;
    float* e2 = isG ? e2g : (float*)nullptr;
    const int N = isG ? NG : ND;
    const int row0 = blk * 128;
    // ---- stage A-tile (x rows, bf16, swizzled): thread t -> row t>>1, 8 k-chunks ----
    {
        const int row = t >> 1, q8 = t & 1;
        const int gr = row0 + row;
        #pragma unroll
        for (int c = 0; c < 8; ++c) {
            const int kc = q8 * 8 + c;
            float4 l0 = make_float4(0.f, 0.f, 0.f, 0.f), l1 = l0;
            if (gr < N) {
                l0 = *(const float4*)(x + (size_t)gr * 128 + kc * 8);
                l1 = *(const float4*)(x + (size_t)gr * 128 + kc * 8 + 4);
            }
            int4 u;
            u.x = (int)f2bf(l0.x) | ((int)f2bf(l0.y) << 16);
            u.y = (int)f2bf(l0.z) | ((int)f2bf(l0.w) << 16);
            u.z = (int)f2bf(l1.x) | ((int)f2bf(l1.y) << 16);
            u.w = (int)f2bf(l1.z) | ((int)f2bf(l1.w) << 16);
            const int chunk = row * 16 + kc;
            const int chunk_sw = chunk ^ (row & 7);
            *(int4*)((char*)atile + chunk_sw * 16) = u;
        }
    }
    __syncthreads();
    const int w = t >> 6, l = t & 63;
    const int lrow = l & 15, lk = l >> 4;
    f32x4 acc[2][10];
    #pragma unroll
    for (int a = 0; a < 2; ++a)
        #pragma unroll
        for (int ct = 0; ct < 10; ++ct) { acc[a][ct][0] = 0.f; acc[a][ct][1] = 0.f; acc[a][ct][2] = 0.f; acc[a][ct][3] = 0.f; }
    #pragma unroll
    for (int ks = 0; ks < 4; ++ks) {
        short8 xfr[2];
        #pragma unroll
        for (int a = 0; a < 2; ++a) {
            const int rowl = w * 32 + a * 16 + lrow;
            const int chunk = rowl * 16 + ks * 4 + lk;
            const int chunk_sw = chunk ^ (rowl & 7);
            xfr[a] = *(short8*)((char*)atile + chunk_sw * 16);
        }
        #pragma unroll
        for (int ct = 0; ct < 10; ++ct) {
            const unsigned short* bp = BExt + ((size_t)(ct * 16 + lrow) * 128 + ks * 32 + lk * 8);
            short8 wfr = *(const short8*)bp;
            // swapped: A = W-frag, B = x-frag  -> lane's col(n)=x-row=lrow, row(m)=W-col=lk*4+r
            acc[0][ct] = __builtin_amdgcn_mfma_f32_16x16x32_bf16(wfr, xfr[0], acc[0][ct], 0, 0, 0);
            acc[1][ct] = __builtin_amdgcn_mfma_f32_16x16x32_bf16(wfr, xfr[1], acc[1][ct], 0, 0, 0);
        }
    }
    // ---- epilogue: lane owns one x-row per a; 4 consecutive W-cols per (ct) ----
    #pragma unroll
    for (int a = 0; a < 2; ++a) {
        const int grow = row0 + w * 32 + a * 16 + lrow;
        if (grow < N) {
            #pragma unroll
            for (int ct = 0; ct < 8; ++ct) {
                const int col = ct * 16 + lk * 4;
                float4 bv = *(const float4*)(bias + col);
                int2 u;
                u.x = (int)f2bf(acc[a][ct][0] + bv.x) | ((int)f2bf(acc[a][ct][1] + bv.y) << 16);
                u.y = (int)f2bf(acc[a][ct][2] + bv.z) | ((int)f2bf(acc[a][ct][3] + bv.w) << 16);
                *(int2*)(hout + (size_t)grow * 128 + col) = u;
            }
            #pragma unroll
            for (int r = 0; r < 4; ++r) {
                const int ecol = lk * 4 + r;           // 0..15
                const int head = ecol & 7;
                float v = acc[a][8][r] + beArr[ecol];
                if (ecol < 8) { if (e0) e0[(size_t)grow * 8 + head] = v; }
                else          { if (e1) e1[(size_t)grow * 8 + head] = v; }
            }
            if (e2) {
                #pragma unroll
                for (int r = 0; r < 4; ++r) {
                    const int ecol = lk * 4 + r;
                    if (ecol < 8) e2[(size_t)grow * 8 + ecol] = acc[a][9][r] + beArr[16 + ecol];
                }
            }
        }
    }
}

// ================= two-level bucket CSR build =================
__global__ __launch_bounds__(256) void bucket_hist(
    const int* __restrict__ dstg, int Eg, const int* __restrict__ dstd, int Ed,
    int NBg, int NBtot, int* __restrict__ bucketCnt)
{
    __shared__ int h[1024];
    const int t = threadIdx.x;
    for (int j = t; j < NBtot; j += 256) h[j] = 0;
    __syncthreads();
    const int Etot = Eg + Ed;
    const int base = blockIdx.x * 4096;
    #pragma unroll
    for (int k = 0; k < 16; ++k) {
        int i = base + k * 256 + t;
        if (i < Etot) {
            int b = (i < Eg) ? (dstg[i] >> BSHIFT) : NBg + (dstd[i - Eg] >> BSHIFT);
            atomicAdd(&h[b], 1);
        }
    }
    __syncthreads();
    for (int j = t; j < NBtot; j += 256) {
        int c = h[j];
        if (c) atomicAdd(&bucketCnt[j], c);
    }
}

__global__ void bucket_scan(const int* __restrict__ bucketCnt, int NBtot, int Etot,
                            int* __restrict__ bucketBase, int* __restrict__ bucketCursor)
{
    __shared__ int s[1024];
    int t = threadIdx.x;
    int v = (t < NBtot) ? bucketCnt[t] : 0;
    s[t] = v;
    __syncthreads();
    for (int o = 1; o < 1024; o <<= 1) {
        int add = (t >= o) ? s[t - o] : 0;
        __syncthreads();
        s[t] += add;
        __syncthreads();
    }
    if (t < NBtot) {
        int e = s[t] - v;
        bucketBase[t] = e;
        bucketCursor[t] = e;
    }
    if (t == 0) bucketBase[NBtot] = Etot;
}

__global__ __launch_bounds__(256) void bucket_scatter(
    const int* __restrict__ dstg, const int* __restrict__ srcg, int Eg,
    const int* __restrict__ dstd, const int* __restrict__ srcd, int Ed,
    int NBg, int NBtot, int* __restrict__ bucketCursor, unsigned* __restrict__ coarse)
{
    __shared__ int h[800];
    __shared__ int basearr[800];
    __shared__ int cur[800];
    const int t = threadIdx.x;
    for (int j = t; j < NBtot; j += 256) h[j] = 0;
    __syncthreads();
    const int Etot = Eg + Ed;
    const int base = blockIdx.x * 4096;
    int bk[16];
    unsigned pk[16];
    #pragma unroll
    for (int k = 0; k < 16; ++k) {
        int i = base + k * 256 + t;
        bk[k] = -1;
        if (i < Etot) {
            int dst, src, goff;
            if (i < Eg) { dst = dstg[i]; src = srcg[i]; goff = 0; }
            else        { dst = dstd[i - Eg]; src = srcd[i - Eg]; goff = NBg; }
            bk[k] = goff + (dst >> BSHIFT);
            pk[k] = (unsigned)src | ((unsigned)(dst & 255) << 24);
            atomicAdd(&h[bk[k]], 1);
        }
    }
    __syncthreads();
    for (int j = t; j < NBtot; j += 256) {
        int c = h[j];
        basearr[j] = c ? atomicAdd(&bucketCursor[j], c) : 0;
        cur[j] = 0;
    }
    __syncthreads();
    #pragma unroll
    for (int k = 0; k < 16; ++k) {
        if (bk[k] >= 0) {
            int r = atomicAdd(&cur[bk[k]], 1);
            coarse[basearr[bk[k]] + r] = pk[k];
        }
    }
}

__global__ __launch_bounds__(256) void bucket_sort(
    const unsigned* __restrict__ coarse, const int* __restrict__ bucketBase,
    int NBg, int Eg, int Ed, int N,
    int* __restrict__ offg, int* __restrict__ offd,
    int* __restrict__ srcs_g, int* __restrict__ srcs_d)
{
    __shared__ int hist[256];
    __shared__ int excl[256];
    __shared__ int cur[256];
    const int b = blockIdx.x;
    const int t = threadIdx.x;
    const int s0 = bucketBase[b], s1 = bucketBase[b + 1];
    const int cnt = s1 - s0;
    const bool isg = b < NBg;
    const int d0 = (isg ? b : b - NBg) << BSHIFT;
    hist[t] = 0;
    __syncthreads();
    for (int i = t; i < cnt; i += 256) {
        unsigned p = coarse[s0 + i];
        atomicAdd(&hist[p >> 24], 1);
    }
    __syncthreads();
    int v = hist[t];
    excl[t] = v;
    __syncthreads();
    for (int o = 1; o < 256; o <<= 1) {
        int add = (t >= o) ? excl[t - o] : 0;
        __syncthreads();
        excl[t] += add;
        __syncthreads();
    }
    const int e = excl[t] - v;  // exclusive prefix within bucket
    const int localBase = isg ? s0 : s0 - Eg;
    const int d = d0 + t;
    if (d < N) {
        if (isg) offg[d] = localBase + e;
        else     offd[d] = localBase + e;
    }
    cur[t] = e;
    __syncthreads();
    int* outp = isg ? srcs_g : srcs_d;
    for (int i = t; i < cnt; i += 256) {
        unsigned p = coarse[s0 + i];
        int r = atomicAdd(&cur[p >> 24], 1);
        outp[localBase + r] = (int)(p & 0xFFFFFFu);
    }
    if (b == 0 && t == 0) { offg[N] = Eg; offd[N] = Ed; }
}

// ---------------- fused per-dst-node softmax aggregation (both graphs, 1 dispatch) ----
// xs BF16; f32 accumulate; no-max softmax (logits bounded ~3, shift-invariant).
__global__ __launch_bounds__(256) void aggregate2_kernel(
    const unsigned short* __restrict__ xsA, const float* __restrict__ esrcA,
    const float* __restrict__ edstA, const int* __restrict__ offA,
    const int* __restrict__ srcA, float* __restrict__ outA,
    const unsigned short* __restrict__ xsB, const float* __restrict__ esrcB,
    const float* __restrict__ edstB, const int* __restrict__ offB,
    const int* __restrict__ srcB, float* __restrict__ outB,
    int Nd, int nbA)
{
    __shared__ float exbuf[4][64 * 8];
    const int lane = threadIdx.x & 63;
    const int wslot = threadIdx.x >> 6;
    const bool isA = blockIdx.x < nbA;
    const int blk = isA ? blockIdx.x : blockIdx.x - nbA;
    const unsigned short* xs = isA ? xsA : xsB;
    const float* esrc = isA ? esrcA : esrcB;
    const float* edst = isA ? edstA : edstB;
    const int* off = isA ? offA : offB;
    const int* srcsorted = isA ? srcA : srcB;
    float* outp = isA ? outA : outB;
    const int n = blk * 4 + wslot;
    if (n >= Nd) return;
    const int o0 = off[n], o1 = off[n + 1];
    const int deg = o1 - o0;
    const int li = lane & 31, half = lane >> 5;
    const int j0 = li * 4;
    const int hh = li >> 2;
    if (deg == 0) {
        if (half == 0) *(float4*)(outp + (size_t)n * 128 + j0) = make_float4(0.f, 0.f, 0.f, 0.f);
        return;
    }
    float ed[8];
    {
        float4 a = *(const float4*)(edst + (size_t)n * 8);
        float4 b = *(const float4*)(edst + (size_t)n * 8 + 4);
        ed[0] = a.x; ed[1] = a.y; ed[2] = a.z; ed[3] = a.w;
        ed[4] = b.x; ed[5] = b.y; ed[6] = b.z; ed[7] = b.w;
    }
    if (deg <= 64) {
        const bool act = lane < deg;
        int s = act ? srcsorted[o0 + lane] : 0;
        float exv[8];
        {
            float4 ea = make_float4(0.f, 0.f, 0.f, 0.f), eb = ea;
            if (act) {
                ea = *(const float4*)(esrc + (size_t)s * 8);
                eb = *(const float4*)(esrc + (size_t)s * 8 + 4);
            }
            float a[8] = {ea.x, ea.y, ea.z, ea.w, eb.x, eb.y, eb.z, eb.w};
            #pragma unroll
            for (int h2 = 0; h2 < 8; ++h2)
                exv[h2] = act ? __expf(leakyf(a[h2] + ed[h2])) : 0.f;
        }
        *(float4*)(&exbuf[wslot][lane * 8])     = make_float4(exv[0], exv[1], exv[2], exv[3]);
        *(float4*)(&exbuf[wslot][lane * 8 + 4]) = make_float4(exv[4], exv[5], exv[6], exv[7]);
        float4 num = make_float4(0.f, 0.f, 0.f, 0.f);
        float den = 0.f;
        const int iters = (deg + 1) >> 1;
        #pragma unroll 2
        for (int k = 0; k < iters; ++k) {
            int i = 2 * k + half;
            if (i < deg) {
                int si = __shfl(s, i);
                float wgt = exbuf[wslot][i * 8 + hh];
                int2 xv2 = *(const int2*)(xs + (size_t)si * 128 + j0);
                unsigned ux = (unsigned)xv2.x, uy = (unsigned)xv2.y;
                float x0 = __uint_as_float(ux << 16);
                float x1 = __uint_as_float(ux & 0xFFFF0000u);
                float x2 = __uint_as_float(uy << 16);
                float x3 = __uint_as_float(uy & 0xFFFF0000u);
                num.x = fmaf(wgt, x0, num.x);
                num.y = fmaf(wgt, x1, num.y);
                num.z = fmaf(wgt, x2, num.z);
                num.w = fmaf(wgt, x3, num.w);
                den += wgt;
            }
        }
        num.x += __shfl_xor(num.x, 32);
        num.y += __shfl_xor(num.y, 32);
        num.z += __shfl_xor(num.z, 32);
        num.w += __shfl_xor(num.w, 32);
        den += __shfl_xor(den, 32);
        if (half == 0) {
            float inv = 1.f / (den + 1e-16f);
            float4 r;
            r.x = fmaxf(num.x * inv, 0.f);
            r.y = fmaxf(num.y * inv, 0.f);
            r.z = fmaxf(num.z * inv, 0.f);
            r.w = fmaxf(num.w * inv, 0.f);
            *(float4*)(outp + (size_t)n * 128 + j0) = r;
        }
        return;
    }
    // ---- slow path (deg > 64), no-max version ----
    {
        const int j0b = lane * 2;
        const int h = lane >> 3;
        float edh;
        {
            float u4a = (h & 4) ? ed[4] : ed[0];
            float u4b = (h & 4) ? ed[5] : ed[1];
            float u4c = (h & 4) ? ed[6] : ed[2];
            float u4d = (h & 4) ? ed[7] : ed[3];
            float u2a = (h & 2) ? u4c : u4a;
            float u2b = (h & 2) ? u4d : u4b;
            edh = (h & 1) ? u2b : u2a;
        }
        float den = 0.f, num0 = 0.f, num1 = 0.f;
        for (int base = 0; base < deg; base += 64) {
            int ii = base + lane;
            bool act = ii < deg;
            int sreg = srcsorted[o0 + (act ? ii : 0)];
            int cl = deg - base;
            if (cl > 64) cl = 64;
            for (int i = 0; i < cl; ++i) {
                int s = __shfl(sreg, i);
                float ev = esrc[(size_t)s * 8 + h];
                float ex = __expf(leakyf(ev + edh));
                unsigned uv = *(const unsigned*)(xs + (size_t)s * 128 + j0b);
                float x0 = __uint_as_float(uv << 16);
                float x1 = __uint_as_float(uv & 0xFFFF0000u);
                num0 = fmaf(ex, x0, num0);
                num1 = fmaf(ex, x1, num1);
                den += ex;
            }
        }
        float inv = 1.f / (den + 1e-16f);
        float r0 = num0 * inv, r1 = num1 * inv;
        r0 = r0 > 0.f ? r0 : 0.f;
        r1 = r1 > 0.f ? r1 : 0.f;
        *(float2*)(outp + (size_t)n * 128 + j0b) = make_float2(r0, r1);
    }
}

// ---------------- Wk transpose + bf16 convert (one-time per launch) ----------------
__global__ void wkt_kernel(const float* __restrict__ Wk, unsigned short* __restrict__ WkT) {
    int c = threadIdx.x;  // 128 threads = one column each
    for (int k = 0; k < 128; ++k)
        WkT[c * 128 + k] = f2bf(Wk[(size_t)k * 128 + c]);
}

// ---------------- semantic attention scores via bf16 MFMA ----------------
__global__ __launch_bounds__(256) void score2_mfma(
    const float* __restrict__ gg, const float* __restrict__ dg,
    const unsigned short* __restrict__ WkT,
    const float* __restrict__ bk, const float* __restrict__ q,
    float* __restrict__ scoreAcc, int N)
{
    __shared__ short atile[128 * 128];  // 32 KB bf16, 16B-chunk XOR-swizzled
    __shared__ float sred[4];
    const int t = threadIdx.x;
    const int row0 = blockIdx.x * 64;
    {
        const int row = t >> 1, q8 = t & 1;
        const int gr = row0 + (row & 63);
        const float* srcp = (row < 64) ? gg : dg;
        #pragma unroll
        for (int c = 0; c < 8; ++c) {
            const int kc = q8 * 8 + c;
            float4 l0 = make_float4(0.f, 0.f, 0.f, 0.f), l1 = l0;
            if (gr < N) {
                l0 = *(const float4*)(srcp + (size_t)gr * 128 + kc * 8);
                l1 = *(const float4*)(srcp + (size_t)gr * 128 + kc * 8 + 4);
            }
            int4 u;
            u.x = (int)f2bf(l0.x) | ((int)f2bf(l0.y) << 16);
            u.y = (int)f2bf(l0.z) | ((int)f2bf(l0.w) << 16);
            u.z = (int)f2bf(l1.x) | ((int)f2bf(l1.y) << 16);
            u.w = (int)f2bf(l1.z) | ((int)f2bf(l1.w) << 16);
            const int chunk = row * 16 + kc;
            const int chunk_sw = chunk ^ (row & 7);
            *(int4*)((char*)atile + chunk_sw * 16) = u;
        }
    }
    __syncthreads();
    const int w = t >> 6, l = t & 63;
    const int lrow = l & 15, lk = l >> 4;
    f32x4 acc[2][8];
    #pragma unroll
    for (int a = 0; a < 2; ++a)
        #pragma unroll
        for (int ct = 0; ct < 8; ++ct) { acc[a][ct][0] = 0.f; acc[a][ct][1] = 0.f; acc[a][ct][2] = 0.f; acc[a][ct][3] = 0.f; }
    #pragma unroll
    for (int ks = 0; ks < 4; ++ks) {
        short8 afr[2];
        #pragma unroll
        for (int a = 0; a < 2; ++a) {
            const int rowl = w * 32 + a * 16 + lrow;
            const int chunk = rowl * 16 + ks * 4 + lk;
            const int chunk_sw = chunk ^ (rowl & 7);
            afr[a] = *(short8*)((char*)atile + chunk_sw * 16);
        }
        #pragma unroll
        for (int ct = 0; ct < 8; ++ct) {
            const unsigned short* bp = WkT + ((size_t)(ct * 16 + lrow) * 128 + ks * 32 + lk * 8);
            short8 bfr = *(const short8*)bp;
            acc[0][ct] = __builtin_amdgcn_mfma_f32_16x16x32_bf16(afr[0], bfr, acc[0][ct], 0, 0, 0);
            acc[1][ct] = __builtin_amdgcn_mfma_f32_16x16x32_bf16(afr[1], bfr, acc[1][ct], 0, 0, 0);
        }
    }
    float s = 0.f;
    #pragma unroll
    for (int ct = 0; ct < 8; ++ct) {
        const int col = ct * 16 + lrow;
        const float bkv = bk[col];
        const float qv = q[col];
        #pragma unroll
        for (int a = 0; a < 2; ++a) {
            #pragma unroll
            for (int r = 0; r < 4; ++r) {
                const int rloc = a * 16 + lk * 4 + r;
                const int grow = row0 + ((w * 32 + rloc) & 63);
                if (grow < N) s = fmaf(fast_tanh(acc[a][ct][r] + bkv), qv, s);
            }
        }
    }
    #pragma unroll
    for (int o = 1; o < 64; o <<= 1) s += __shfl_xor(s, o);
    if (l == 0) sred[w] = s;
    __syncthreads();
    if (t == 0) {
        float pg = sred[0] + sred[1];
        float pd = sred[2] + sred[3];
        int slot = blockIdx.x & 63;
        atomicAdd(&scoreAcc[slot], pg);
        atomicAdd(&scoreAcc[64 + slot], pd);
    }
}

// ---------------- tiny: reduce 2x64 score slots -> softmax betas ----------------
__global__ void beta_kernel(float* __restrict__ scoreAcc, float invN) {
    int t = threadIdx.x;  // 64 threads
    float v0 = scoreAcc[t];
    float v1 = scoreAcc[64 + t];
    #pragma unroll
    for (int o = 1; o < 64; o <<= 1) {
        v0 += __shfl_xor(v0, o);
        v1 += __shfl_xor(v1, o);
    }
    if (t == 0) {
        float s0 = v0 * invN, s1 = v1 * invN;
        float mx = fmaxf(s0, s1);
        float e0 = __expf(s0 - mx), e1 = __expf(s1 - mx);
        float inv = 1.f / (e0 + e1);
        scoreAcc[128] = e0 * inv;
        scoreAcc[129] = e1 * inv;
    }
}

// ---------------- final: beta blend + @W_lin + b_lin (W_lin staged in LDS) ----------------
__global__ __launch_bounds__(256) void final_kernel(
    const float* __restrict__ gg, const float* __restrict__ dg,
    const float* __restrict__ beta,   // scoreAcc+128: {beta0, beta1}
    const float* __restrict__ Wl, const float* __restrict__ bl,
    float* __restrict__ outp, int N)
{
    __shared__ float wlds[128 * 64];  // 32 KB — whole W_lin
    __shared__ float glds[32 * 128];  // 16 KB — blended tile
    const int t = threadIdx.x;
    #pragma unroll
    for (int p = 0; p < 8; ++p) {
        int idx = (t + 256 * p) * 4;
        *(float4*)(wlds + idx) = *(const float4*)(Wl + idx);
    }
    const float bet0 = beta[0], bet1 = beta[1];
    const int row0 = blockIdx.x * 32;
    #pragma unroll
    for (int p = 0; p < 4; ++p) {
        int idx = t + 256 * p;
        int r = idx >> 5;
        int c4 = idx & 31;
        float4 a = make_float4(0.f, 0.f, 0.f, 0.f), b = a, g;
        if (row0 + r < N) {
            a = *(const float4*)(gg + (size_t)(row0 + r) * 128 + c4 * 4);
            b = *(const float4*)(dg + (size_t)(row0 + r) * 128 + c4 * 4);
        }
        g.x = bet0 * a.x + bet1 * b.x;
        g.y = bet0 * a.y + bet1 * b.y;
        g.z = bet0 * a.z + bet1 * b.z;
        g.w = bet0 * a.w + bet1 * b.w;
        *(float4*)(glds + r * 128 + c4 * 4) = g;
    }
    __syncthreads();
    const int rg = t >> 5, ct = t & 31;
    float acc[4][2];
    {
        float2 bv = *(const float2*)(bl + ct * 2);
        #pragma unroll
        for (int rr = 0; rr < 4; ++rr) { acc[rr][0] = bv.x; acc[rr][1] = bv.y; }
    }
    #pragma unroll 2
    for (int i = 0; i < 128; i += 4) {
        float4 xv[4];
        #pragma unroll
        for (int rr = 0; rr < 4; ++rr) xv[rr] = *(const float4*)(glds + (rg + 8 * rr) * 128 + i);
        #pragma unroll
        for (int qq = 0; qq < 4; ++qq) {
            float2 wv = *(const float2*)(wlds + (i + qq) * 64 + ct * 2);
            #pragma unroll
            for (int rr = 0; rr < 4; ++rr) {
                float xs = ((const float*)&xv[rr])[qq];
                acc[rr][0] = fmaf(xs, wv.x, acc[rr][0]);
                acc[rr][1] = fmaf(xs, wv.y, acc[rr][1]);
            }
        }
    }
    #pragma unroll
    for (int rr = 0; rr < 4; ++rr) {
        int grow = row0 + rg + 8 * rr;
        if (grow < N)
            *(float2*)(outp + (size_t)grow * 64 + ct * 2) = make_float2(acc[rr][0], acc[rr][1]);
    }
}

extern "C" void kernel_launch(void* const* d_in, const int* in_sizes, int n_in,
                              void* d_out, int out_size, void* d_ws, size_t ws_size,
                              hipStream_t stream) {
    (void)n_in; (void)out_size; (void)ws_size;
    const float* x_gene = (const float*)d_in[0];
    const float* x_dis  = (const float*)d_in[1];
    const int* eg_src   = (const int*)d_in[2];
    const int* eg_dst   = (const int*)d_in[3];
    const int* edg_src  = (const int*)d_in[4];
    const int* edg_dst  = (const int*)d_in[5];
    const float* W_gene = (const float*)d_in[6];
    const float* b_gene = (const float*)d_in[7];
    const float* W_dis  = (const float*)d_in[8];
    const float* b_dis  = (const float*)d_in[9];
    const float* att_src_gg = (const float*)d_in[10];
    const float* att_dst_gg = (const float*)d_in[11];
    const float* att_src_dg = (const float*)d_in[12];
    const float* att_dst_dg = (const float*)d_in[13];
    const float* Wk    = (const float*)d_in[14];
    const float* bk    = (const float*)d_in[15];
    const float* q     = (const float*)d_in[16];
    const float* W_lin = (const float*)d_in[17];
    const float* b_lin = (const float*)d_in[18];
    float* out = (float*)d_out;

    const int NG_ = in_sizes[0] / 128;
    const int ND_ = in_sizes[1] / 128;
    const int EG_ = in_sizes[2];
    const int EDG_ = in_sizes[4];

    char* w = (char*)d_ws;
    auto alloc = [&](size_t bytes) -> char* {
        char* p = w;
        w += (bytes + 255) & ~(size_t)255;
        return p;
    };
    unsigned short* hg = (unsigned short*)alloc((size_t)NG_ * 128 * 2);  // bf16
    unsigned short* hd = (unsigned short*)alloc((size_t)ND_ * 128 * 2);  // bf16
    float* e_src_gg = (float*)alloc((size_t)NG_ * 8 * 4);
    float* e_dst_gg = (float*)alloc((size_t)NG_ * 8 * 4);
    float* e_dst_dg = (float*)alloc((size_t)NG_ * 8 * 4);
    float* e_src_dg = (float*)alloc((size_t)ND_ * 8 * 4);
    float* out_gg   = (float*)alloc((size_t)NG_ * 128 * 4);
    float* out_dg   = (float*)alloc((size_t)NG_ * 128 * 4);
    int* offg  = (int*)alloc((size_t)(NG_ + 1) * 4);
    int* offd  = (int*)alloc((size_t)(NG_ + 1) * 4);
    int* srcs_g = (int*)alloc((size_t)EG_ * 4);
    int* srcs_d = (int*)alloc((size_t)EDG_ * 4);
    unsigned* coarse = (unsigned*)alloc((size_t)(EG_ + EDG_) * 4);
    int* bucketCnt    = (int*)alloc(4096);
    int* bucketBase   = (int*)alloc(4096);
    int* bucketCursor = (int*)alloc(4096);
    unsigned short* WkT   = (unsigned short*)alloc(128 * 128 * 2);
    unsigned short* bextg = (unsigned short*)alloc(160 * 128 * 2);
    unsigned short* bextd = (unsigned short*)alloc(160 * 128 * 2);
    float* beg = (float*)alloc(256);
    float* bed = (float*)alloc(256);
    float* score = (float*)alloc(1024);

    const int NBg = (NG_ + 255) >> BSHIFT;   // 391 for NG=100000
    const int NBtot = 2 * NBg;               // 782 <= 1024 (single-block scan) and <= 800 (LDS arrays)
    const int Etot = EG_ + EDG_;
    const int nbE = (Etot + 4095) / 4096;

    // 0. build extended B matrices (parallel) + WkT
    bext2_kernel<<<20, 256, 0, stream>>>(W_gene, b_gene,
        att_src_gg, att_dst_gg, att_dst_dg, bextg, beg);
    bext2_kernel<<<20, 256, 0, stream>>>(W_dis, b_dis,
        att_src_dg, (const float*)nullptr, (const float*)nullptr, bextd, bed);
    wkt_kernel<<<1, 128, 0, stream>>>(Wk, WkT);

    // 1. projections via operand-swapped MFMA (both node types, one dispatch)
    {
        const int nbG = (NG_ + 127) / 128;
        const int nbD = (ND_ + 127) / 128;
        proj_mfma2<<<nbG + nbD, 256, 0, stream>>>(
            x_gene, bextg, b_gene, beg, hg, e_src_gg, e_dst_gg, e_dst_dg, NG_, nbG,
            x_dis, bextd, b_dis, bed, hd, e_src_dg, ND_);
    }

    // 2. two-level bucket CSR build (both graphs)
    hipMemsetAsync(bucketCnt, 0, (size_t)NBtot * 4, stream);
    bucket_hist<<<nbE, 256, 0, stream>>>(eg_dst, EG_, edg_dst, EDG_, NBg, NBtot, bucketCnt);
    bucket_scan<<<1, 1024, 0, stream>>>(bucketCnt, NBtot, Etot, bucketBase, bucketCursor);
    bucket_scatter<<<nbE, 256, 0, stream>>>(
        eg_dst, eg_src, EG_, edg_dst, edg_src, EDG_, NBg, NBtot, bucketCursor, coarse);
    bucket_sort<<<NBtot, 256, 0, stream>>>(
        coarse, bucketBase, NBg, EG_, EDG_, NG_, offg, offd, srcs_g, srcs_d);

    // 3. fused aggregates (both graphs, one dispatch; bf16 gather, no-max softmax)
    {
        const int nbA = (NG_ + 3) / 4;
        aggregate2_kernel<<<2 * nbA, 256, 0, stream>>>(
            hg, e_src_gg, e_dst_gg, offg, srcs_g, out_gg,
            hd, e_src_dg, e_dst_dg, offd, srcs_d, out_dg,
            NG_, nbA);
    }

    // 4. semantic attention scores via bf16 MFMA + beta
    hipMemsetAsync(score, 0, 512, stream);
    score2_mfma<<<(NG_ + 63) / 64, 256, 0, stream>>>(out_gg, out_dg, WkT, bk, q, score, NG_);
    beta_kernel<<<1, 64, 0, stream>>>(score, 1.0f / (float)NG_);

    // 5. blend + final linear
    final_kernel<<<(NG_ + 31) / 32, 256, 0, stream>>>(
        out_gg, out_dg, score + 128, W_lin, b_lin, out, NG_);
}